// Round 8
// baseline (1304.881 us; speedup 1.0000x reference)
//
#include <hip/hip_runtime.h>

// Problem constants (fixed by the reference)
#define D_MODEL   256
#define NQ        1600
#define BATCH     2
#define NHEAD     8
#define HDIM      32
#define S_TOTAL   5440
#define D_FFN     1024
#define NUM_LAYERS 6

#define M_Q   (BATCH * NQ)       // 3200
#define M_V   (BATCH * S_TOTAL)  // 10880
#define ROW_ELEMS ((size_t)M_Q * D_MODEL)   // 819200

using short8  = __attribute__((ext_vector_type(8))) short;
using short4v = __attribute__((ext_vector_type(4))) short;
using floatx4 = __attribute__((ext_vector_type(4))) float;

// 16x16x16 bf16 MFMA builtin name differs across LLVM versions
#if __has_builtin(__builtin_amdgcn_mfma_f32_16x16x16_bf16)
  #define MFMA16K16(a,b,c) __builtin_amdgcn_mfma_f32_16x16x16_bf16((a),(b),(c),0,0,0)
#else
  #define MFMA16K16(a,b,c) __builtin_amdgcn_mfma_f32_16x16x16bf16_1k((a),(b),(c),0,0,0)
#endif

#if __has_builtin(__builtin_amdgcn_exp2f)
  #define EXP2F(x) __builtin_amdgcn_exp2f(x)
#else
  #define EXP2F(x) exp2f(x)
#endif

__device__ __forceinline__ ushort f2bf(float f) {
    union { float f; unsigned u; } x; x.f = f;
    unsigned r = (x.u + 0x7fffu + ((x.u >> 16) & 1u)) >> 16;
    return (ushort)r;
}
__device__ __forceinline__ ushort f2bf_trunc(float f) {
    union { float f; unsigned u; } x; x.f = f;
    return (ushort)(x.u >> 16);
}
__device__ __forceinline__ float bf2f(ushort b) {
    union { unsigned u; float f; } x; x.u = ((unsigned)b) << 16;
    return x.f;
}

// ---------------------------------------------------------------------------
// Segmented bf16 MFMA GEMM (LDS-staged). Each bn-block (64 cols) descriptor:
//   mode 0: fp32 store  1: relu+bf16  2: bf16  3: bf16 transposed (b,col,q)
// mblk: valid 64-row blocks for this segment. 64x64 tile, BK=32, 4 waves.
// ---------------------------------------------------------------------------
struct GSeg {
    const ushort* A;
    const ushort* W;      // pre-offset to this 64-col block
    const float*  bias;   // pre-offset
    void*         C;      // col-offset pre-applied (modes 0-2)
    int           ldc;
    int           mode;
    int           mblk;
    float         scale;
};
struct GArgs { GSeg s[16]; };

__global__ __launch_bounds__(256) void gemm_multi(GArgs args, int K)
{
    const GSeg sg = args.s[blockIdx.y];
    if ((int)blockIdx.x >= sg.mblk) return;
    __shared__ ushort Al[64][40];
    __shared__ ushort Bl[64][40];
    const int tid  = threadIdx.x;
    const int bm   = blockIdx.x * 64;
    const int lr   = tid >> 2;
    const int lc   = tid & 3;
    const int wave = tid >> 6;
    const int lane = tid & 63;
    const int mo   = (wave & 1) * 32;
    const int no   = (wave >> 1) * 32;
    const int row16 = lane & 15;
    const int quad  = lane >> 4;

    floatx4 acc[2][2] = {};

    const ushort* aG = sg.A + (size_t)(bm + lr) * K + lc * 8;
    const ushort* wG = sg.W + (size_t)lr * K + lc * 8;

    for (int k0 = 0; k0 < K; k0 += 32) {
        __syncthreads();
        *(short8*)&Al[lr][lc * 8] = *(const short8*)(aG + k0);
        *(short8*)&Bl[lr][lc * 8] = *(const short8*)(wG + k0);
        __syncthreads();
        short8 af0 = *(const short8*)&Al[mo + row16][quad * 8];
        short8 af1 = *(const short8*)&Al[mo + 16 + row16][quad * 8];
        short8 bf0 = *(const short8*)&Bl[no + row16][quad * 8];
        short8 bf1 = *(const short8*)&Bl[no + 16 + row16][quad * 8];
        acc[0][0] = __builtin_amdgcn_mfma_f32_16x16x32_bf16(af0, bf0, acc[0][0], 0, 0, 0);
        acc[0][1] = __builtin_amdgcn_mfma_f32_16x16x32_bf16(af0, bf1, acc[0][1], 0, 0, 0);
        acc[1][0] = __builtin_amdgcn_mfma_f32_16x16x32_bf16(af1, bf0, acc[1][0], 0, 0, 0);
        acc[1][1] = __builtin_amdgcn_mfma_f32_16x16x32_bf16(af1, bf1, acc[1][1], 0, 0, 0);
    }

#pragma unroll
    for (int mi = 0; mi < 2; ++mi)
#pragma unroll
        for (int ni = 0; ni < 2; ++ni) {
            const int col = no + ni * 16 + row16;
            const float bv = sg.bias[col];
            if (sg.mode == 3) {
                const int rowb = bm + mo + mi * 16 + quad * 4;
                const int b    = rowb / NQ;
                const int mloc = rowb - b * NQ;
                ushort4 st;
                st.x = f2bf((acc[mi][ni][0] + bv) * sg.scale);
                st.y = f2bf((acc[mi][ni][1] + bv) * sg.scale);
                st.z = f2bf((acc[mi][ni][2] + bv) * sg.scale);
                st.w = f2bf((acc[mi][ni][3] + bv) * sg.scale);
                *(ushort4*)((ushort*)sg.C + (size_t)b * (256 * NQ) + (size_t)col * NQ + mloc) = st;
            } else {
#pragma unroll
                for (int r = 0; r < 4; ++r) {
                    const int row = bm + mo + mi * 16 + quad * 4 + r;
                    float v = (acc[mi][ni][r] + bv) * sg.scale;
                    if (sg.mode == 0)
                        ((float*)sg.C)[(size_t)row * sg.ldc + col] = v;
                    else if (sg.mode == 1)
                        ((ushort*)sg.C)[(size_t)row * sg.ldc + col] = f2bf(fmaxf(v, 0.f));
                    else
                        ((ushort*)sg.C)[(size_t)row * sg.ldc + col] = f2bf(v);
                }
            }
        }
}

// ---------------------------------------------------------------------------
// GEMM (64 rows x FULL 256 cols per block) + fused residual + LayerNorm.
// outp = fp32 LN result; outp_h = bf16; qadd_h = bf16(LN + qpos).
// Block: 256 thr = 4 waves; wave w owns cols [w*64, w*64+64). BK=32.
// A: (M,K) bf16. W: (256,K) bf16. resid: (M,256) fp32 (read-modify row).
// ---------------------------------------------------------------------------
__global__ __launch_bounds__(256) void gemm_ln(const ushort* __restrict__ A,
                                               const ushort* __restrict__ W,
                                               const float* __restrict__ bias,
                                               const float* __restrict__ g,
                                               const float* __restrict__ bt,
                                               const float* __restrict__ qpos,
                                               const float* __restrict__ resid,
                                               float* __restrict__ outp,
                                               ushort* __restrict__ outp_h,
                                               ushort* __restrict__ qadd_h,
                                               int K)
{
    __shared__ ushort St[320][40];      // rows 0..63 = A-tile, 64..319 = W rows
    __shared__ float  R1[4][64], R2[4][64];
    const int tid  = threadIdx.x;
    const int bm   = blockIdx.x * 64;
    const int wave = tid >> 6, lane = tid & 63;
    const int lr   = lane & 15, quad = lane >> 4;

    floatx4 acc[4][4] = {};

    for (int k0 = 0; k0 < K; k0 += 32) {
        __syncthreads();
#pragma unroll
        for (int i = 0; i < 5; ++i) {
            const int c = tid + i * 256;        // 0..1279
            const int row = c >> 2, kc = c & 3;
            const ushort* src = (row < 64)
                ? (A + (size_t)(bm + row) * K + k0 + kc * 8)
                : (W + (size_t)(row - 64) * K + k0 + kc * 8);
            *(short8*)&St[row][kc * 8] = *(const short8*)src;
        }
        __syncthreads();
        short8 af[4], bf[4];
#pragma unroll
        for (int mg = 0; mg < 4; ++mg) af[mg] = *(const short8*)&St[mg * 16 + lr][quad * 8];
#pragma unroll
        for (int ng = 0; ng < 4; ++ng) bf[ng] = *(const short8*)&St[64 + wave * 64 + ng * 16 + lr][quad * 8];
#pragma unroll
        for (int mg = 0; mg < 4; ++mg)
#pragma unroll
            for (int ng = 0; ng < 4; ++ng)
                acc[mg][ng] = __builtin_amdgcn_mfma_f32_16x16x32_bf16(af[mg], bf[ng], acc[mg][ng], 0, 0, 0);
    }

    // v = acc + bias + residual
#pragma unroll
    for (int mg = 0; mg < 4; ++mg)
#pragma unroll
        for (int ng = 0; ng < 4; ++ng) {
            const int col = wave * 64 + ng * 16 + lr;
            const float bv = bias[col];
#pragma unroll
            for (int r = 0; r < 4; ++r) {
                const int row = bm + mg * 16 + quad * 4 + r;
                acc[mg][ng][r] += bv + resid[(size_t)row * 256 + col];
            }
        }

    // row partials over this wave's 64 cols
#pragma unroll
    for (int mg = 0; mg < 4; ++mg)
#pragma unroll
        for (int r = 0; r < 4; ++r) {
            float s1 = acc[mg][0][r] + acc[mg][1][r] + acc[mg][2][r] + acc[mg][3][r];
            float s2 = acc[mg][0][r]*acc[mg][0][r] + acc[mg][1][r]*acc[mg][1][r]
                     + acc[mg][2][r]*acc[mg][2][r] + acc[mg][3][r]*acc[mg][3][r];
            s1 += __shfl_xor(s1, 1); s2 += __shfl_xor(s2, 1);
            s1 += __shfl_xor(s1, 2); s2 += __shfl_xor(s2, 2);
            s1 += __shfl_xor(s1, 4); s2 += __shfl_xor(s2, 4);
            s1 += __shfl_xor(s1, 8); s2 += __shfl_xor(s2, 8);
            if (lr == 0) {
                const int rl = mg * 16 + quad * 4 + r;
                R1[wave][rl] = s1;
                R2[wave][rl] = s2;
            }
        }
    __syncthreads();

#pragma unroll
    for (int mg = 0; mg < 4; ++mg)
#pragma unroll
        for (int r = 0; r < 4; ++r) {
            const int rl = mg * 16 + quad * 4 + r;
            const float tot1 = R1[0][rl] + R1[1][rl] + R1[2][rl] + R1[3][rl];
            const float tot2 = R2[0][rl] + R2[1][rl] + R2[2][rl] + R2[3][rl];
            const float mu  = tot1 * (1.f / 256.f);
            const float var = tot2 * (1.f / 256.f) - mu * mu;
            const float rs  = rsqrtf(var + 1e-5f);
            const int row = bm + rl;
#pragma unroll
            for (int ng = 0; ng < 4; ++ng) {
                const int col = wave * 64 + ng * 16 + lr;
                const size_t idx = (size_t)row * 256 + col;
                const float rv = (acc[mg][ng][r] - mu) * rs * g[col] + bt[col];
                outp[idx]   = rv;
                outp_h[idx] = f2bf(rv);
                qadd_h[idx] = f2bf(rv + qpos[idx]);
            }
        }
}

// ---------------------------------------------------------------------------
// MFMA flash self-attention, transpose-free PV path.
// S^T = K·Q^T via mfma(kf, qf): per lane q = lane&15, keys = quad*4+r —
// exactly the A-operand layout of mfma_f32_16x16x16_bf16. exp in-register,
// pack to bf16x4, feed straight into PV (B = Vt b64 fragment). Zero LDS in
// the K-loop. Fixed-shift softmax (Q pre-scaled by log2e/sqrt(32)).
// Grid (B*NHEAD, NQ/16); 4 waves split the 25 K-tiles; LDS combine at end.
// ---------------------------------------------------------------------------
#define FSHIFT 16.0f

__global__ __launch_bounds__(256) void attn_mfma(const ushort* __restrict__ Qh,
                                                 const ushort* __restrict__ Kh,
                                                 const ushort* __restrict__ Vt,
                                                 ushort* __restrict__ Oh)
{
    const int bh = blockIdx.x;
    const int h  = bh & 7, b = bh >> 3;
    const int q0 = blockIdx.y * 16;
    const int tid  = threadIdx.x;
    const int wave = tid >> 6, lane = tid & 63;
    const int lr   = lane & 15, quad = lane >> 4;

    __shared__ float Ol[4][16][33];   // per-wave partial O (q x d)
    __shared__ float Ll[4][16];       // per-wave partial lsum

    const ushort* Kb = Kh + (size_t)b * NQ * 256 + h * 32;
    const ushort* Vb = Vt + (size_t)bh * 32 * NQ;

    // Q fragment (B-operand of S^T MFMA): row q0+lr, dims quad*8..+8
    const short8 qf = *(const short8*)(Qh + (size_t)(b * NQ + q0 + lr) * 256 + h * 32 + quad * 8);

    float lsum = 0.f;                  // partial for q = lr over this lane's keys
    floatx4 accO[2] = {};
    const floatx4 zero = {0.f, 0.f, 0.f, 0.f};

    for (int t = wave; t < NQ / 64; t += 4) {
        const int k0 = t * 64;
#pragma unroll
        for (int cb = 0; cb < 4; ++cb) {
            // K fragment (A-operand): row = key = k0+cb*16+lr, dims quad*8..+8
            const short8 kf = *(const short8*)(Kb + (size_t)(k0 + cb * 16 + lr) * 256 + quad * 8);
            const floatx4 st = __builtin_amdgcn_mfma_f32_16x16x32_bf16(kf, qf, zero, 0, 0, 0);
            // st[r]: q = lr, key = k0 + cb*16 + quad*4 + r
            short4v pf;
#pragma unroll
            for (int r = 0; r < 4; ++r) {
                const float p = EXP2F(fminf(st[r], 100.f) - FSHIFT);
                lsum += p;
                pf[r] = (short)f2bf_trunc(p);
            }
            // PV: A = pf (m=q, k=key quad*4+j), B = Vt fragment (n=d, k=key)
            const short4v v0 = *(const short4v*)(Vb + (size_t)lr * NQ + k0 + cb * 16 + quad * 4);
            const short4v v1 = *(const short4v*)(Vb + (size_t)(16 + lr) * NQ + k0 + cb * 16 + quad * 4);
            accO[0] = MFMA16K16(pf, v0, accO[0]);
            accO[1] = MFMA16K16(pf, v1, accO[1]);
        }
    }

    // lsum: reduce across the 4 quads holding the same q = lr
    lsum += __shfl_xor(lsum, 16);
    lsum += __shfl_xor(lsum, 32);
    if (quad == 0) Ll[wave][lr] = lsum;
    // accO: q = quad*4+r, d = lr (+16)
#pragma unroll
    for (int r = 0; r < 4; ++r) {
        const int q = quad * 4 + r;
        Ol[wave][q][lr]      = accO[0][r];
        Ol[wave][q][16 + lr] = accO[1][r];
    }
    __syncthreads();

    // combine 4 wave-partials: 512 outputs, 2 per thread
#pragma unroll
    for (int i = 0; i < 2; ++i) {
        const int idx = tid + i * 256;
        const int q = idx >> 5, d = idx & 31;
        const float o  = Ol[0][q][d] + Ol[1][q][d] + Ol[2][q][d] + Ol[3][q][d];
        const float lt = Ll[0][q] + Ll[1][q] + Ll[2][q] + Ll[3][q];
        Oh[(size_t)(b * NQ + q0 + q) * 256 + h * 32 + d] = f2bf(o / lt);
    }
}

// ---------------------------------------------------------------------------
// Segmented fp32 -> bf16 conversion (weights + src), one launch.
// ---------------------------------------------------------------------------
struct CvtSeg { const float* in; ushort* out; int n4; };
struct CvtArgs { CvtSeg seg[11]; };

__global__ __launch_bounds__(256) void convert_kernel(CvtArgs args)
{
    const CvtSeg sg = args.seg[blockIdx.y];
    const int i = blockIdx.x * 256 + threadIdx.x;
    if (i < sg.n4) {
        float4 v = ((const float4*)sg.in)[i];
        ushort4 o;
        o.x = f2bf(v.x); o.y = f2bf(v.y); o.z = f2bf(v.z); o.w = f2bf(v.w);
        ((ushort4*)sg.out)[i] = o;
    }
}

// out = tgt (fp32), out_h = bf16(tgt), qadd_h = bf16(tgt + qpos)
__global__ __launch_bounds__(256) void init_out_kernel(const float* __restrict__ tgt,
                                                       const float* __restrict__ qpos,
                                                       float* __restrict__ out,
                                                       ushort* __restrict__ out_h,
                                                       ushort* __restrict__ qadd_h, int n4)
{
    const int i = blockIdx.x * 256 + threadIdx.x;
    if (i < n4) {
        float4 v = ((const float4*)tgt)[i];
        float4 p = ((const float4*)qpos)[i];
        ((float4*)out)[i] = v;
        ushort4 o, qa;
        o.x = f2bf(v.x); o.y = f2bf(v.y); o.z = f2bf(v.z); o.w = f2bf(v.w);
        qa.x = f2bf(v.x + p.x); qa.y = f2bf(v.y + p.y);
        qa.z = f2bf(v.z + p.z); qa.w = f2bf(v.w + p.w);
        ((ushort4*)out_h)[i] = o;
        ((ushort4*)qadd_h)[i] = qa;
    }
}

// ---------------------------------------------------------------------------
// Deformable sampling with inline softmax over the 16 attention weights.
// Block per (b,q); thread = (head h = tid>>5, chan c = tid&31).
// ---------------------------------------------------------------------------
__global__ __launch_bounds__(256) void sample_kernel(const ushort* __restrict__ value,
                                                     const float* __restrict__ off,
                                                     const float* __restrict__ aw,
                                                     const float* __restrict__ ref,
                                                     ushort* __restrict__ outp_h)
{
    const int bq = blockIdx.x;
    const int b  = bq / NQ;
    const int h  = threadIdx.x >> 5;
    const int c  = threadIdx.x & 31;

    const float* offrow = off + (size_t)bq * 256 + h * 32;
    const float* awrow  = aw  + (size_t)bq * 128 + h * 16;
    const float* refrow = ref + (size_t)bq * 8;

    float w16[16];
    {
        float mx = -1e30f;
#pragma unroll
        for (int i = 0; i < 16; ++i) { w16[i] = awrow[i]; mx = fmaxf(mx, w16[i]); }
        float sum = 0.f;
#pragma unroll
        for (int i = 0; i < 16; ++i) { w16[i] = __expf(w16[i] - mx); sum += w16[i]; }
        const float inv = 1.f / sum;
#pragma unroll
        for (int i = 0; i < 16; ++i) w16[i] *= inv;
    }

    const int HL[4]  = {64, 32, 16, 8};
    const int WLv[4] = {64, 32, 16, 8};
    const int S0[4]  = {0, 4096, 5120, 5376};

    float acc = 0.f;
#pragma unroll
    for (int l = 0; l < 4; ++l) {
        const int Hl = HL[l], Wl = WLv[l];
        const float rx = refrow[l * 2 + 0];
        const float ry = refrow[l * 2 + 1];
        const size_t lvl_base = ((size_t)b * S_TOTAL + S0[l]);
#pragma unroll
        for (int p = 0; p < 4; ++p) {
            const float ox = offrow[l * 8 + p * 2 + 0];
            const float oy = offrow[l * 8 + p * 2 + 1];
            const float w  = w16[l * 4 + p];
            const float locx = rx + ox / (float)Wl;
            const float locy = ry + oy / (float)Hl;
            const float x = locx * (float)Wl - 0.5f;
            const float y = locy * (float)Hl - 0.5f;
            const float x0f = floorf(x), y0f = floorf(y);
            const float wx1 = x - x0f, wy1 = y - y0f;
            const int x0 = (int)x0f, y0 = (int)y0f;
#pragma unroll
            for (int dy = 0; dy < 2; ++dy) {
                const int yi = y0 + dy;
                const float wy = dy ? wy1 : (1.f - wy1);
                const bool vy = (yi >= 0) && (yi <= Hl - 1);
                const int yc = min(max(yi, 0), Hl - 1);
#pragma unroll
                for (int dx = 0; dx < 2; ++dx) {
                    const int xi = x0 + dx;
                    const float wx = dx ? wx1 : (1.f - wx1);
                    const bool vx = (xi >= 0) && (xi <= Wl - 1);
                    const int xc = min(max(xi, 0), Wl - 1);
                    const float gv = bf2f(value[((lvl_base + (size_t)yc * Wl + xc)) * 256 + h * 32 + c]);
                    acc += (vx && vy) ? gv * (wx * wy * w) : 0.f;
                }
            }
        }
    }
    outp_h[(size_t)bq * D_MODEL + h * 32 + c] = f2bf(acc);
}

// ---------------------------------------------------------------------------
// Host-side orchestration
// ---------------------------------------------------------------------------
extern "C" void kernel_launch(void* const* d_in, const int* in_sizes, int n_in,
                              void* d_out, int out_size, void* d_ws, size_t ws_size,
                              hipStream_t stream)
{
    const float* tgt  = (const float*)d_in[0];
    const float* qpos = (const float*)d_in[1];
    const float* refp = (const float*)d_in[2];
    const float* src  = (const float*)d_in[3];

    // ---- workspace carve-up ----
    float* bufOff = (float*)d_ws;                   // 819200
    float* bufAw  = bufOff + ROW_ELEMS;             // 409600

    ushort* out_h   = (ushort*)(bufAw + (size_t)M_Q * 128);
    ushort* qadd_h  = out_h   + ROW_ELEMS;
    ushort* bufX_h  = qadd_h  + ROW_ELEMS;          // attn-out / sample-out
    ushort* bufQh   = bufX_h  + ROW_ELEMS;
    ushort* bufKh   = bufQh   + ROW_ELEMS;
    ushort* bufVt   = bufKh   + ROW_ELEMS;          // V^T (b,h,d,q)
    ushort* bufF_h  = bufVt   + ROW_ELEMS;          // 3276800 ffn hidden
    ushort* bufVal  = bufF_h  + (size_t)M_Q * D_FFN;   // 2785280 deform value
    ushort* src_h   = bufVal  + (size_t)M_V * D_MODEL; // 2785280
    ushort* wpool   = src_h   + (size_t)M_V * D_MODEL;

    ushort* wq_h    = wpool;
    ushort* wk_h    = wq_h    + 393216;
    ushort* wv_h    = wk_h    + 393216;
    ushort* wo_h    = wv_h    + 393216;
    ushort* woff_h  = wo_h    + 393216;
    ushort* wattn_h = woff_h  + 393216;
    ushort* wval_h  = wattn_h + 196608;
    ushort* wout_h  = wval_h  + 393216;
    ushort* w1_h    = wout_h  + 393216;
    ushort* w2_h    = w1_h    + 1572864;

    float* out = (float*)d_out;

    // ---- conversions ----
    CvtArgs ca;
    ca.seg[0]  = { src,                    src_h,   (int)((size_t)M_V * D_MODEL / 4) };
    ca.seg[1]  = { (const float*)d_in[4],  wq_h,    393216 / 4 };
    ca.seg[2]  = { (const float*)d_in[6],  wk_h,    393216 / 4 };
    ca.seg[3]  = { (const float*)d_in[8],  wv_h,    393216 / 4 };
    ca.seg[4]  = { (const float*)d_in[10], wo_h,    393216 / 4 };
    ca.seg[5]  = { (const float*)d_in[14], woff_h,  393216 / 4 };
    ca.seg[6]  = { (const float*)d_in[16], wattn_h, 196608 / 4 };
    ca.seg[7]  = { (const float*)d_in[18], wval_h,  393216 / 4 };
    ca.seg[8]  = { (const float*)d_in[20], wout_h,  393216 / 4 };
    ca.seg[9]  = { (const float*)d_in[24], w1_h,    1572864 / 4 };
    ca.seg[10] = { (const float*)d_in[26], w2_h,    1572864 / 4 };
    convert_kernel<<<dim3(2720, 11), 256, 0, stream>>>(ca);

    init_out_kernel<<<800, 256, 0, stream>>>(tgt, qpos, out, out_h, qadd_h, (int)(ROW_ELEMS / 4));

    // Q pre-scale: log2(e)/sqrt(32) so attention computes exp2 directly
    const float QSCALE = 0.1767766952966369f * 1.4426950408889634f;
    const int MB_Q = M_Q / 64;   // 50
    const int MB_V = M_V / 64;   // 170

    for (int l = 0; l < NUM_LAYERS; ++l) {
        const float* sa_b_q    = (const float*)d_in[5]  + (size_t)l * 256;
        const float* sa_b_k    = (const float*)d_in[7]  + (size_t)l * 256;
        const float* sa_b_v    = (const float*)d_in[9]  + (size_t)l * 256;
        const float* sa_b_o    = (const float*)d_in[11] + (size_t)l * 256;
        const float* ln2_g     = (const float*)d_in[12] + (size_t)l * 256;
        const float* ln2_b     = (const float*)d_in[13] + (size_t)l * 256;
        const float* ca_b_off  = (const float*)d_in[15] + (size_t)l * 256;
        const float* ca_b_attn = (const float*)d_in[17] + (size_t)l * 128;
        const float* ca_b_val  = (const float*)d_in[19] + (size_t)l * 256;
        const float* ca_b_out  = (const float*)d_in[21] + (size_t)l * 256;
        const float* ln1_g     = (const float*)d_in[22] + (size_t)l * 256;
        const float* ln1_b     = (const float*)d_in[23] + (size_t)l * 256;
        const float* ffn_b1    = (const float*)d_in[25] + (size_t)l * 1024;
        const float* ffn_b2    = (const float*)d_in[27] + (size_t)l * 256;
        const float* ln3_g     = (const float*)d_in[28] + (size_t)l * 256;
        const float* ln3_b     = (const float*)d_in[29] + (size_t)l * 256;

        const ushort* wq = wq_h    + (size_t)l * 65536;
        const ushort* wk = wk_h    + (size_t)l * 65536;
        const ushort* wv = wv_h    + (size_t)l * 65536;
        const ushort* wo = wo_h    + (size_t)l * 65536;
        const ushort* wf = woff_h  + (size_t)l * 65536;
        const ushort* wa = wattn_h + (size_t)l * 32768;
        const ushort* wl = wval_h  + (size_t)l * 65536;
        const ushort* wu = wout_h  + (size_t)l * 65536;
        const ushort* w1 = w1_h    + (size_t)l * 262144;
        const ushort* w2 = w2_h    + (size_t)l * 262144;

        GArgs ga;

        // ---- QKV projections + deform value projection (one dispatch) ----
        for (int i = 0; i < 4; ++i) {
            ga.s[i]      = { qadd_h, wq + (size_t)i * 64 * 256, sa_b_q + i * 64, bufQh + i * 64, 256, 2, MB_Q, QSCALE };
            ga.s[4 + i]  = { qadd_h, wk + (size_t)i * 64 * 256, sa_b_k + i * 64, bufKh + i * 64, 256, 2, MB_Q, 1.f };
            ga.s[8 + i]  = { out_h,  wv + (size_t)i * 64 * 256, sa_b_v + i * 64, bufVt + (size_t)i * 64 * NQ, 256, 3, MB_Q, 1.f };
            ga.s[12 + i] = { src_h,  wl + (size_t)i * 64 * 256, ca_b_val + i * 64, bufVal + i * 64, 256, 2, MB_V, 1.f };
        }
        gemm_multi<<<dim3(MB_V, 16), 256, 0, stream>>>(ga, 256);

        attn_mfma<<<dim3(16, NQ / 16), 256, 0, stream>>>(bufQh, bufKh, bufVt, bufX_h);

        // ---- attn out-proj + residual + LN (fused) ----
        gemm_ln<<<MB_Q, 256, 0, stream>>>(bufX_h, wo, sa_b_o, ln2_g, ln2_b, qpos,
                                          out, out, out_h, qadd_h, 256);

        // ---- Deformable cross-attention ----
        for (int i = 0; i < 4; ++i)
            ga.s[i] = { qadd_h, wf + (size_t)i * 64 * 256, ca_b_off + i * 64, bufOff + i * 64, 256, 0, MB_Q, 1.f };
        for (int i = 0; i < 2; ++i)
            ga.s[4 + i] = { qadd_h, wa + (size_t)i * 64 * 256, ca_b_attn + i * 64, bufAw + i * 64, 128, 0, MB_Q, 1.f };
        gemm_multi<<<dim3(MB_Q, 6), 256, 0, stream>>>(ga, 256);

        sample_kernel<<<M_Q, 256, 0, stream>>>(bufVal, bufOff, bufAw, refp, bufX_h);

        gemm_ln<<<MB_Q, 256, 0, stream>>>(bufX_h, wu, ca_b_out, ln1_g, ln1_b, qpos,
                                          out, out, out_h, qadd_h, 256);

        // ---- FFN ----
        for (int i = 0; i < 16; ++i)
            ga.s[i] = { out_h, w1 + (size_t)i * 64 * 256, ffn_b1 + i * 64, bufF_h + i * 64, 1024, 1, MB_Q, 1.f };
        gemm_multi<<<dim3(MB_Q, 16), 256, 0, stream>>>(ga, 256);

        gemm_ln<<<MB_Q, 256, 0, stream>>>(bufF_h, w2, ffn_b2, ln3_g, ln3_b, qpos,
                                          out, out, out_h, qadd_h, 1024);
    }

    (void)in_sizes; (void)n_in; (void)out_size; (void)ws_size;
}

// Round 9
// 1127.377 us; speedup vs baseline: 1.1574x; 1.1574x over previous
//
#include <hip/hip_runtime.h>

// Problem constants (fixed by the reference)
#define D_MODEL   256
#define NQ        1600
#define BATCH     2
#define NHEAD     8
#define HDIM      32
#define S_TOTAL   5440
#define D_FFN     1024
#define NUM_LAYERS 6

#define M_Q   (BATCH * NQ)       // 3200
#define M_V   (BATCH * S_TOTAL)  // 10880
#define ROW_ELEMS ((size_t)M_Q * D_MODEL)   // 819200

using short8  = __attribute__((ext_vector_type(8))) short;
using short4v = __attribute__((ext_vector_type(4))) short;
using floatx4 = __attribute__((ext_vector_type(4))) float;

// 16x16x16 bf16 MFMA builtin name differs across LLVM versions
#if __has_builtin(__builtin_amdgcn_mfma_f32_16x16x16_bf16)
  #define MFMA16K16(a,b,c) __builtin_amdgcn_mfma_f32_16x16x16_bf16((a),(b),(c),0,0,0)
#else
  #define MFMA16K16(a,b,c) __builtin_amdgcn_mfma_f32_16x16x16bf16_1k((a),(b),(c),0,0,0)
#endif

#if __has_builtin(__builtin_amdgcn_exp2f)
  #define EXP2F(x) __builtin_amdgcn_exp2f(x)
#else
  #define EXP2F(x) exp2f(x)
#endif

__device__ __forceinline__ ushort f2bf(float f) {
    union { float f; unsigned u; } x; x.f = f;
    unsigned r = (x.u + 0x7fffu + ((x.u >> 16) & 1u)) >> 16;
    return (ushort)r;
}
__device__ __forceinline__ ushort f2bf_trunc(float f) {
    union { float f; unsigned u; } x; x.f = f;
    return (ushort)(x.u >> 16);
}
__device__ __forceinline__ float bf2f(ushort b) {
    union { unsigned u; float f; } x; x.u = ((unsigned)b) << 16;
    return x.f;
}

// ---------------------------------------------------------------------------
// Segmented bf16 MFMA GEMM (LDS-staged). Each bn-block (64 cols) descriptor:
//   mode 0: fp32 store  1: relu+bf16  2: bf16  3: bf16 transposed (b,col,q)
// mblk: valid 64-row blocks for this segment. 64x64 tile, BK=32, 4 waves.
// ---------------------------------------------------------------------------
struct GSeg {
    const ushort* A;
    const ushort* W;      // pre-offset to this 64-col block
    const float*  bias;   // pre-offset
    void*         C;      // col-offset pre-applied (modes 0-2)
    int           ldc;
    int           mode;
    int           mblk;
    float         scale;
};
struct GArgs { GSeg s[16]; };

__global__ __launch_bounds__(256) void gemm_multi(GArgs args, int K)
{
    const GSeg sg = args.s[blockIdx.y];
    if ((int)blockIdx.x >= sg.mblk) return;
    __shared__ ushort Al[64][40];
    __shared__ ushort Bl[64][40];
    const int tid  = threadIdx.x;
    const int bm   = blockIdx.x * 64;
    const int lr   = tid >> 2;
    const int lc   = tid & 3;
    const int wave = tid >> 6;
    const int lane = tid & 63;
    const int mo   = (wave & 1) * 32;
    const int no   = (wave >> 1) * 32;
    const int row16 = lane & 15;
    const int quad  = lane >> 4;

    floatx4 acc[2][2] = {};

    const ushort* aG = sg.A + (size_t)(bm + lr) * K + lc * 8;
    const ushort* wG = sg.W + (size_t)lr * K + lc * 8;

    for (int k0 = 0; k0 < K; k0 += 32) {
        __syncthreads();
        *(short8*)&Al[lr][lc * 8] = *(const short8*)(aG + k0);
        *(short8*)&Bl[lr][lc * 8] = *(const short8*)(wG + k0);
        __syncthreads();
        short8 af0 = *(const short8*)&Al[mo + row16][quad * 8];
        short8 af1 = *(const short8*)&Al[mo + 16 + row16][quad * 8];
        short8 bf0 = *(const short8*)&Bl[no + row16][quad * 8];
        short8 bf1 = *(const short8*)&Bl[no + 16 + row16][quad * 8];
        acc[0][0] = __builtin_amdgcn_mfma_f32_16x16x32_bf16(af0, bf0, acc[0][0], 0, 0, 0);
        acc[0][1] = __builtin_amdgcn_mfma_f32_16x16x32_bf16(af0, bf1, acc[0][1], 0, 0, 0);
        acc[1][0] = __builtin_amdgcn_mfma_f32_16x16x32_bf16(af1, bf0, acc[1][0], 0, 0, 0);
        acc[1][1] = __builtin_amdgcn_mfma_f32_16x16x32_bf16(af1, bf1, acc[1][1], 0, 0, 0);
    }

#pragma unroll
    for (int mi = 0; mi < 2; ++mi)
#pragma unroll
        for (int ni = 0; ni < 2; ++ni) {
            const int col = no + ni * 16 + row16;
            const float bv = sg.bias[col];
            if (sg.mode == 3) {
                const int rowb = bm + mo + mi * 16 + quad * 4;
                const int b    = rowb / NQ;
                const int mloc = rowb - b * NQ;
                ushort4 st;
                st.x = f2bf((acc[mi][ni][0] + bv) * sg.scale);
                st.y = f2bf((acc[mi][ni][1] + bv) * sg.scale);
                st.z = f2bf((acc[mi][ni][2] + bv) * sg.scale);
                st.w = f2bf((acc[mi][ni][3] + bv) * sg.scale);
                *(ushort4*)((ushort*)sg.C + (size_t)b * (256 * NQ) + (size_t)col * NQ + mloc) = st;
            } else {
#pragma unroll
                for (int r = 0; r < 4; ++r) {
                    const int row = bm + mo + mi * 16 + quad * 4 + r;
                    float v = (acc[mi][ni][r] + bv) * sg.scale;
                    if (sg.mode == 0)
                        ((float*)sg.C)[(size_t)row * sg.ldc + col] = v;
                    else if (sg.mode == 1)
                        ((ushort*)sg.C)[(size_t)row * sg.ldc + col] = f2bf(fmaxf(v, 0.f));
                    else
                        ((ushort*)sg.C)[(size_t)row * sg.ldc + col] = f2bf(v);
                }
            }
        }
}

// ---------------------------------------------------------------------------
// MFMA flash self-attention, transpose-free PV + EXPLICIT NEXT-TILE PREFETCH.
// S^T = K·Q^T: per lane q = lane&15, keys = quad*4+r — exactly the A-operand
// layout of mfma_f32_16x16x16_bf16. exp in-register -> PV directly; zero LDS
// in the K-loop. Each iteration issues tile t+4's 12 fragment loads BEFORE
// computing tile t, so the waitcnt lands after ~360 cyc of compute (the r8
// profile showed ~875 cyc/iter = bare L2 latency, loads issued just-in-time).
// Fixed-shift softmax (Q pre-scaled by log2e/sqrt(32)).
// Grid (B*NHEAD, NQ/16); 4 waves split the 25 K-tiles; LDS combine at end.
// ---------------------------------------------------------------------------
#define FSHIFT 16.0f

__global__ __launch_bounds__(256) void attn_mfma(const ushort* __restrict__ Qh,
                                                 const ushort* __restrict__ Kh,
                                                 const ushort* __restrict__ Vt,
                                                 ushort* __restrict__ Oh)
{
    const int bh = blockIdx.x;
    const int h  = bh & 7, b = bh >> 3;
    const int q0 = blockIdx.y * 16;
    const int tid  = threadIdx.x;
    const int wave = tid >> 6, lane = tid & 63;
    const int lr   = lane & 15, quad = lane >> 4;

    __shared__ float Ol[4][16][33];   // per-wave partial O (q x d)
    __shared__ float Ll[4][16];       // per-wave partial lsum

    const ushort* Kb = Kh + (size_t)b * NQ * 256 + h * 32;
    const ushort* Vb = Vt + (size_t)bh * 32 * NQ;

    // Q fragment (B-operand of S^T MFMA): row q0+lr, dims quad*8..+8
    const short8 qf = *(const short8*)(Qh + (size_t)(b * NQ + q0 + lr) * 256 + h * 32 + quad * 8);

    float lsum = 0.f;
    floatx4 accO[2] = {};
    const floatx4 zero = {0.f, 0.f, 0.f, 0.f};

    const int NT = NQ / 64;   // 25
    int t = wave;

    // preload tile t
    short8  kf[4];
    short4v v0[4], v1[4];
#pragma unroll
    for (int cb = 0; cb < 4; ++cb) {
        kf[cb] = *(const short8*)(Kb + (size_t)(t * 64 + cb * 16 + lr) * 256 + quad * 8);
        v0[cb] = *(const short4v*)(Vb + (size_t)lr * NQ        + t * 64 + cb * 16 + quad * 4);
        v1[cb] = *(const short4v*)(Vb + (size_t)(16 + lr) * NQ + t * 64 + cb * 16 + quad * 4);
    }

    while (true) {
        // issue next tile's loads before computing current (clamped on last iter)
        const int tn = (t + 4 < NT) ? (t + 4) : t;
        short8  kfn[4];
        short4v v0n[4], v1n[4];
#pragma unroll
        for (int cb = 0; cb < 4; ++cb) {
            kfn[cb] = *(const short8*)(Kb + (size_t)(tn * 64 + cb * 16 + lr) * 256 + quad * 8);
            v0n[cb] = *(const short4v*)(Vb + (size_t)lr * NQ        + tn * 64 + cb * 16 + quad * 4);
            v1n[cb] = *(const short4v*)(Vb + (size_t)(16 + lr) * NQ + tn * 64 + cb * 16 + quad * 4);
        }

        // compute current tile
#pragma unroll
        for (int cb = 0; cb < 4; ++cb) {
            const floatx4 st = __builtin_amdgcn_mfma_f32_16x16x32_bf16(kf[cb], qf, zero, 0, 0, 0);
            // st[r]: q = lr, key = t*64 + cb*16 + quad*4 + r
            short4v pf;
#pragma unroll
            for (int r = 0; r < 4; ++r) {
                const float p = EXP2F(fminf(st[r], 100.f) - FSHIFT);
                lsum += p;
                pf[r] = (short)f2bf_trunc(p);
            }
            accO[0] = MFMA16K16(pf, v0[cb], accO[0]);
            accO[1] = MFMA16K16(pf, v1[cb], accO[1]);
        }

        if (t + 4 >= NT) break;
        t += 4;
#pragma unroll
        for (int cb = 0; cb < 4; ++cb) { kf[cb] = kfn[cb]; v0[cb] = v0n[cb]; v1[cb] = v1n[cb]; }
    }

    // lsum: reduce across the 4 quads holding the same q = lr
    lsum += __shfl_xor(lsum, 16);
    lsum += __shfl_xor(lsum, 32);
    if (quad == 0) Ll[wave][lr] = lsum;
    // accO: q = quad*4+r, d = lr (+16)
#pragma unroll
    for (int r = 0; r < 4; ++r) {
        const int q = quad * 4 + r;
        Ol[wave][q][lr]      = accO[0][r];
        Ol[wave][q][16 + lr] = accO[1][r];
    }
    __syncthreads();

    // combine 4 wave-partials: 512 outputs, 2 per thread
#pragma unroll
    for (int i = 0; i < 2; ++i) {
        const int idx = tid + i * 256;
        const int q = idx >> 5, d = idx & 31;
        const float o  = Ol[0][q][d] + Ol[1][q][d] + Ol[2][q][d] + Ol[3][q][d];
        const float lt = Ll[0][q] + Ll[1][q] + Ll[2][q] + Ll[3][q];
        Oh[(size_t)(b * NQ + q0 + q) * 256 + h * 32 + d] = f2bf(o / lt);
    }
}

// ---------------------------------------------------------------------------
// Segmented fp32 -> bf16 conversion (weights + src), one launch.
// ---------------------------------------------------------------------------
struct CvtSeg { const float* in; ushort* out; int n4; };
struct CvtArgs { CvtSeg seg[11]; };

__global__ __launch_bounds__(256) void convert_kernel(CvtArgs args)
{
    const CvtSeg sg = args.seg[blockIdx.y];
    const int i = blockIdx.x * 256 + threadIdx.x;
    if (i < sg.n4) {
        float4 v = ((const float4*)sg.in)[i];
        ushort4 o;
        o.x = f2bf(v.x); o.y = f2bf(v.y); o.z = f2bf(v.z); o.w = f2bf(v.w);
        ((ushort4*)sg.out)[i] = o;
    }
}

// out = tgt (fp32), out_h = bf16(tgt), qadd_h = bf16(tgt + qpos)
__global__ __launch_bounds__(256) void init_out_kernel(const float* __restrict__ tgt,
                                                       const float* __restrict__ qpos,
                                                       float* __restrict__ out,
                                                       ushort* __restrict__ out_h,
                                                       ushort* __restrict__ qadd_h, int n4)
{
    const int i = blockIdx.x * 256 + threadIdx.x;
    if (i < n4) {
        float4 v = ((const float4*)tgt)[i];
        float4 p = ((const float4*)qpos)[i];
        ((float4*)out)[i] = v;
        ushort4 o, qa;
        o.x = f2bf(v.x); o.y = f2bf(v.y); o.z = f2bf(v.z); o.w = f2bf(v.w);
        qa.x = f2bf(v.x + p.x); qa.y = f2bf(v.y + p.y);
        qa.z = f2bf(v.z + p.z); qa.w = f2bf(v.w + p.w);
        ((ushort4*)out_h)[i] = o;
        ((ushort4*)qadd_h)[i] = qa;
    }
}

// ---------------------------------------------------------------------------
// Fused residual + LayerNorm -> out fp32, out_h bf16, qadd_h = bf16(ln + qpos).
// One block per row. In-place safe.
// ---------------------------------------------------------------------------
__global__ __launch_bounds__(256) void residual_ln_kernel(const float* __restrict__ x,
                                                          const float* __restrict__ t2,
                                                          const float* __restrict__ g,
                                                          const float* __restrict__ bt,
                                                          const float* __restrict__ qpos,
                                                          float* __restrict__ outp,
                                                          ushort* __restrict__ outp_h,
                                                          ushort* __restrict__ qadd_h)
{
    const int row = blockIdx.x;
    const int c = threadIdx.x;
    const size_t idx = (size_t)row * D_MODEL + c;
    float v = x[idx] + t2[idx];

    float s = v, s2 = v * v;
#pragma unroll
    for (int off = 32; off; off >>= 1) {
        s  += __shfl_xor(s,  off);
        s2 += __shfl_xor(s2, off);
    }
    __shared__ float ws[4], ws2[4];
    const int wid = c >> 6;
    if ((c & 63) == 0) { ws[wid] = s; ws2[wid] = s2; }
    __syncthreads();
    const float tot  = ws[0] + ws[1] + ws[2] + ws[3];
    const float tot2 = ws2[0] + ws2[1] + ws2[2] + ws2[3];
    const float mu  = tot * (1.f / 256.f);
    const float var = tot2 * (1.f / 256.f) - mu * mu;
    const float r = (v - mu) * rsqrtf(var + 1e-5f) * g[c] + bt[c];
    outp[idx] = r;
    outp_h[idx] = f2bf(r);
    qadd_h[idx] = f2bf(r + qpos[idx]);
}

// ---------------------------------------------------------------------------
// Deformable sampling with inline softmax over the 16 attention weights.
// Block per (b,q); thread = (head h = tid>>5, chan c = tid&31).
// ---------------------------------------------------------------------------
__global__ __launch_bounds__(256) void sample_kernel(const ushort* __restrict__ value,
                                                     const float* __restrict__ off,
                                                     const float* __restrict__ aw,
                                                     const float* __restrict__ ref,
                                                     ushort* __restrict__ outp_h)
{
    const int bq = blockIdx.x;
    const int b  = bq / NQ;
    const int h  = threadIdx.x >> 5;
    const int c  = threadIdx.x & 31;

    const float* offrow = off + (size_t)bq * 256 + h * 32;
    const float* awrow  = aw  + (size_t)bq * 128 + h * 16;
    const float* refrow = ref + (size_t)bq * 8;

    float w16[16];
    {
        float mx = -1e30f;
#pragma unroll
        for (int i = 0; i < 16; ++i) { w16[i] = awrow[i]; mx = fmaxf(mx, w16[i]); }
        float sum = 0.f;
#pragma unroll
        for (int i = 0; i < 16; ++i) { w16[i] = __expf(w16[i] - mx); sum += w16[i]; }
        const float inv = 1.f / sum;
#pragma unroll
        for (int i = 0; i < 16; ++i) w16[i] *= inv;
    }

    const int HL[4]  = {64, 32, 16, 8};
    const int WLv[4] = {64, 32, 16, 8};
    const int S0[4]  = {0, 4096, 5120, 5376};

    float acc = 0.f;
#pragma unroll
    for (int l = 0; l < 4; ++l) {
        const int Hl = HL[l], Wl = WLv[l];
        const float rx = refrow[l * 2 + 0];
        const float ry = refrow[l * 2 + 1];
        const size_t lvl_base = ((size_t)b * S_TOTAL + S0[l]);
#pragma unroll
        for (int p = 0; p < 4; ++p) {
            const float ox = offrow[l * 8 + p * 2 + 0];
            const float oy = offrow[l * 8 + p * 2 + 1];
            const float w  = w16[l * 4 + p];
            const float locx = rx + ox / (float)Wl;
            const float locy = ry + oy / (float)Hl;
            const float x = locx * (float)Wl - 0.5f;
            const float y = locy * (float)Hl - 0.5f;
            const float x0f = floorf(x), y0f = floorf(y);
            const float wx1 = x - x0f, wy1 = y - y0f;
            const int x0 = (int)x0f, y0 = (int)y0f;
#pragma unroll
            for (int dy = 0; dy < 2; ++dy) {
                const int yi = y0 + dy;
                const float wy = dy ? wy1 : (1.f - wy1);
                const bool vy = (yi >= 0) && (yi <= Hl - 1);
                const int yc = min(max(yi, 0), Hl - 1);
#pragma unroll
                for (int dx = 0; dx < 2; ++dx) {
                    const int xi = x0 + dx;
                    const float wx = dx ? wx1 : (1.f - wx1);
                    const bool vx = (xi >= 0) && (xi <= Wl - 1);
                    const int xc = min(max(xi, 0), Wl - 1);
                    const float gv = bf2f(value[((lvl_base + (size_t)yc * Wl + xc)) * 256 + h * 32 + c]);
                    acc += (vx && vy) ? gv * (wx * wy * w) : 0.f;
                }
            }
        }
    }
    outp_h[(size_t)bq * D_MODEL + h * 32 + c] = f2bf(acc);
}

// ---------------------------------------------------------------------------
// Host-side orchestration
// ---------------------------------------------------------------------------
extern "C" void kernel_launch(void* const* d_in, const int* in_sizes, int n_in,
                              void* d_out, int out_size, void* d_ws, size_t ws_size,
                              hipStream_t stream)
{
    const float* tgt  = (const float*)d_in[0];
    const float* qpos = (const float*)d_in[1];
    const float* refp = (const float*)d_in[2];
    const float* src  = (const float*)d_in[3];

    // ---- workspace carve-up ----
    float* bufT   = (float*)d_ws;                   // 819200 (GEMM fp32 out pre-LN)
    float* bufOff = bufT   + ROW_ELEMS;             // 819200
    float* bufAw  = bufOff + ROW_ELEMS;             // 409600

    ushort* out_h   = (ushort*)(bufAw + (size_t)M_Q * 128);
    ushort* qadd_h  = out_h   + ROW_ELEMS;
    ushort* bufX_h  = qadd_h  + ROW_ELEMS;          // attn-out / sample-out
    ushort* bufQh   = bufX_h  + ROW_ELEMS;
    ushort* bufKh   = bufQh   + ROW_ELEMS;
    ushort* bufVt   = bufKh   + ROW_ELEMS;          // V^T (b,h,d,q)
    ushort* bufF_h  = bufVt   + ROW_ELEMS;          // 3276800 ffn hidden
    ushort* bufVal  = bufF_h  + (size_t)M_Q * D_FFN;   // 2785280 deform value
    ushort* src_h   = bufVal  + (size_t)M_V * D_MODEL; // 2785280
    ushort* wpool   = src_h   + (size_t)M_V * D_MODEL;

    ushort* wq_h    = wpool;
    ushort* wk_h    = wq_h    + 393216;
    ushort* wv_h    = wk_h    + 393216;
    ushort* wo_h    = wv_h    + 393216;
    ushort* woff_h  = wo_h    + 393216;
    ushort* wattn_h = woff_h  + 393216;
    ushort* wval_h  = wattn_h + 196608;
    ushort* wout_h  = wval_h  + 393216;
    ushort* w1_h    = wout_h  + 393216;
    ushort* w2_h    = w1_h    + 1572864;

    float* out = (float*)d_out;

    // ---- conversions ----
    CvtArgs ca;
    ca.seg[0]  = { src,                    src_h,   (int)((size_t)M_V * D_MODEL / 4) };
    ca.seg[1]  = { (const float*)d_in[4],  wq_h,    393216 / 4 };
    ca.seg[2]  = { (const float*)d_in[6],  wk_h,    393216 / 4 };
    ca.seg[3]  = { (const float*)d_in[8],  wv_h,    393216 / 4 };
    ca.seg[4]  = { (const float*)d_in[10], wo_h,    393216 / 4 };
    ca.seg[5]  = { (const float*)d_in[14], woff_h,  393216 / 4 };
    ca.seg[6]  = { (const float*)d_in[16], wattn_h, 196608 / 4 };
    ca.seg[7]  = { (const float*)d_in[18], wval_h,  393216 / 4 };
    ca.seg[8]  = { (const float*)d_in[20], wout_h,  393216 / 4 };
    ca.seg[9]  = { (const float*)d_in[24], w1_h,    1572864 / 4 };
    ca.seg[10] = { (const float*)d_in[26], w2_h,    1572864 / 4 };
    convert_kernel<<<dim3(2720, 11), 256, 0, stream>>>(ca);

    init_out_kernel<<<800, 256, 0, stream>>>(tgt, qpos, out, out_h, qadd_h, (int)(ROW_ELEMS / 4));

    // Q pre-scale: log2(e)/sqrt(32) so attention computes exp2 directly
    const float QSCALE = 0.1767766952966369f * 1.4426950408889634f;
    const int MB_Q = M_Q / 64;   // 50
    const int MB_V = M_V / 64;   // 170

    for (int l = 0; l < NUM_LAYERS; ++l) {
        const float* sa_b_q    = (const float*)d_in[5]  + (size_t)l * 256;
        const float* sa_b_k    = (const float*)d_in[7]  + (size_t)l * 256;
        const float* sa_b_v    = (const float*)d_in[9]  + (size_t)l * 256;
        const float* sa_b_o    = (const float*)d_in[11] + (size_t)l * 256;
        const float* ln2_g     = (const float*)d_in[12] + (size_t)l * 256;
        const float* ln2_b     = (const float*)d_in[13] + (size_t)l * 256;
        const float* ca_b_off  = (const float*)d_in[15] + (size_t)l * 256;
        const float* ca_b_attn = (const float*)d_in[17] + (size_t)l * 128;
        const float* ca_b_val  = (const float*)d_in[19] + (size_t)l * 256;
        const float* ca_b_out  = (const float*)d_in[21] + (size_t)l * 256;
        const float* ln1_g     = (const float*)d_in[22] + (size_t)l * 256;
        const float* ln1_b     = (const float*)d_in[23] + (size_t)l * 256;
        const float* ffn_b1    = (const float*)d_in[25] + (size_t)l * 1024;
        const float* ffn_b2    = (const float*)d_in[27] + (size_t)l * 256;
        const float* ln3_g     = (const float*)d_in[28] + (size_t)l * 256;
        const float* ln3_b     = (const float*)d_in[29] + (size_t)l * 256;

        const ushort* wq = wq_h    + (size_t)l * 65536;
        const ushort* wk = wk_h    + (size_t)l * 65536;
        const ushort* wv = wv_h    + (size_t)l * 65536;
        const ushort* wo = wo_h    + (size_t)l * 65536;
        const ushort* wf = woff_h  + (size_t)l * 65536;
        const ushort* wa = wattn_h + (size_t)l * 32768;
        const ushort* wl = wval_h  + (size_t)l * 65536;
        const ushort* wu = wout_h  + (size_t)l * 65536;
        const ushort* w1 = w1_h    + (size_t)l * 262144;
        const ushort* w2 = w2_h    + (size_t)l * 262144;

        GArgs ga;

        // ---- QKV projections + deform value projection (one dispatch) ----
        for (int i = 0; i < 4; ++i) {
            ga.s[i]      = { qadd_h, wq + (size_t)i * 64 * 256, sa_b_q + i * 64, bufQh + i * 64, 256, 2, MB_Q, QSCALE };
            ga.s[4 + i]  = { qadd_h, wk + (size_t)i * 64 * 256, sa_b_k + i * 64, bufKh + i * 64, 256, 2, MB_Q, 1.f };
            ga.s[8 + i]  = { out_h,  wv + (size_t)i * 64 * 256, sa_b_v + i * 64, bufVt + (size_t)i * 64 * NQ, 256, 3, MB_Q, 1.f };
            ga.s[12 + i] = { src_h,  wl + (size_t)i * 64 * 256, ca_b_val + i * 64, bufVal + i * 64, 256, 2, MB_V, 1.f };
        }
        gemm_multi<<<dim3(MB_V, 16), 256, 0, stream>>>(ga, 256);

        attn_mfma<<<dim3(16, NQ / 16), 256, 0, stream>>>(bufQh, bufKh, bufVt, bufX_h);

        for (int i = 0; i < 4; ++i)
            ga.s[i] = { bufX_h, wo + (size_t)i * 64 * 256, sa_b_o + i * 64, bufT + i * 64, 256, 0, MB_Q, 1.f };
        gemm_multi<<<dim3(MB_Q, 4), 256, 0, stream>>>(ga, 256);

        residual_ln_kernel<<<M_Q, 256, 0, stream>>>(out, bufT, ln2_g, ln2_b, qpos, out, out_h, qadd_h);

        // ---- Deformable cross-attention ----
        for (int i = 0; i < 4; ++i)
            ga.s[i] = { qadd_h, wf + (size_t)i * 64 * 256, ca_b_off + i * 64, bufOff + i * 64, 256, 0, MB_Q, 1.f };
        for (int i = 0; i < 2; ++i)
            ga.s[4 + i] = { qadd_h, wa + (size_t)i * 64 * 256, ca_b_attn + i * 64, bufAw + i * 64, 128, 0, MB_Q, 1.f };
        gemm_multi<<<dim3(MB_Q, 6), 256, 0, stream>>>(ga, 256);

        sample_kernel<<<M_Q, 256, 0, stream>>>(bufVal, bufOff, bufAw, refp, bufX_h);

        for (int i = 0; i < 4; ++i)
            ga.s[i] = { bufX_h, wu + (size_t)i * 64 * 256, ca_b_out + i * 64, bufT + i * 64, 256, 0, MB_Q, 1.f };
        gemm_multi<<<dim3(MB_Q, 4), 256, 0, stream>>>(ga, 256);

        residual_ln_kernel<<<M_Q, 256, 0, stream>>>(out, bufT, ln1_g, ln1_b, qpos, out, out_h, qadd_h);

        // ---- FFN ----
        for (int i = 0; i < 16; ++i)
            ga.s[i] = { out_h, w1 + (size_t)i * 64 * 256, ffn_b1 + i * 64, bufF_h + i * 64, 1024, 1, MB_Q, 1.f };
        gemm_multi<<<dim3(MB_Q, 16), 256, 0, stream>>>(ga, 256);

        for (int i = 0; i < 4; ++i)
            ga.s[i] = { bufF_h, w2 + (size_t)i * 64 * 1024, ffn_b2 + i * 64, bufT + i * 64, 256, 0, MB_Q, 1.f };
        gemm_multi<<<dim3(MB_Q, 4), 256, 0, stream>>>(ga, 1024);

        residual_ln_kernel<<<M_Q, 256, 0, stream>>>(out, bufT, ln3_g, ln3_b, qpos, out, out_h, qadd_h);
    }

    (void)in_sizes; (void)n_in; (void)out_size; (void)ws_size;
}

// Round 10
// 903.251 us; speedup vs baseline: 1.4446x; 1.2481x over previous
//
#include <hip/hip_runtime.h>

// Problem constants (fixed by the reference)
#define D_MODEL   256
#define NQ        1600
#define BATCH     2
#define NHEAD     8
#define HDIM      32
#define S_TOTAL   5440
#define D_FFN     1024
#define NUM_LAYERS 6

#define M_Q   (BATCH * NQ)       // 3200
#define M_V   (BATCH * S_TOTAL)  // 10880
#define ROW_ELEMS ((size_t)M_Q * D_MODEL)   // 819200

using short8  = __attribute__((ext_vector_type(8))) short;
using short4v = __attribute__((ext_vector_type(4))) short;
using floatx4 = __attribute__((ext_vector_type(4))) float;

// 16x16x16 bf16 MFMA builtin name differs across LLVM versions
#if __has_builtin(__builtin_amdgcn_mfma_f32_16x16x16_bf16)
  #define MFMA16K16(a,b,c) __builtin_amdgcn_mfma_f32_16x16x16_bf16((a),(b),(c),0,0,0)
#else
  #define MFMA16K16(a,b,c) __builtin_amdgcn_mfma_f32_16x16x16bf16_1k((a),(b),(c),0,0,0)
#endif

#if __has_builtin(__builtin_amdgcn_exp2f)
  #define EXP2F(x) __builtin_amdgcn_exp2f(x)
#else
  #define EXP2F(x) exp2f(x)
#endif

__device__ __forceinline__ ushort f2bf(float f) {
    union { float f; unsigned u; } x; x.f = f;
    unsigned r = (x.u + 0x7fffu + ((x.u >> 16) & 1u)) >> 16;
    return (ushort)r;
}
__device__ __forceinline__ ushort f2bf_trunc(float f) {
    union { float f; unsigned u; } x; x.f = f;
    return (ushort)(x.u >> 16);
}
__device__ __forceinline__ float bf2f(ushort b) {
    union { unsigned u; float f; } x; x.u = ((unsigned)b) << 16;
    return x.f;
}

// ---------------------------------------------------------------------------
// Segmented bf16 MFMA GEMM (LDS-staged). Each bn-block (64 cols) descriptor:
//   mode 0: fp32 store          1: relu+bf16      2: bf16
//   mode 4: head-major bf16 (b, h=gcol>>5, q, d=gcol&31)  [C pre-offset by h0*NQ*32]
//   mode 5: V chunked-transpose (b, h, q>>2, d, q&3)      [C pre-offset by h0*NQ*32]
// mblk: valid 64-row blocks for this segment. 64x64 tile, BK=32, 4 waves.
// ---------------------------------------------------------------------------
struct GSeg {
    const ushort* A;
    const ushort* W;      // pre-offset to this 64-col block
    const float*  bias;   // pre-offset
    void*         C;      // col-offset pre-applied (modes 0-2); h0*NQ*32 for 4/5
    int           ldc;
    int           mode;
    int           mblk;
    float         scale;
};
struct GArgs { GSeg s[16]; };

__global__ __launch_bounds__(256) void gemm_multi(GArgs args, int K)
{
    const GSeg sg = args.s[blockIdx.y];
    if ((int)blockIdx.x >= sg.mblk) return;
    __shared__ ushort Al[64][40];
    __shared__ ushort Bl[64][40];
    const int tid  = threadIdx.x;
    const int bm   = blockIdx.x * 64;
    const int lr   = tid >> 2;
    const int lc   = tid & 3;
    const int wave = tid >> 6;
    const int lane = tid & 63;
    const int mo   = (wave & 1) * 32;
    const int no   = (wave >> 1) * 32;
    const int row16 = lane & 15;
    const int quad  = lane >> 4;

    floatx4 acc[2][2] = {};

    const ushort* aG = sg.A + (size_t)(bm + lr) * K + lc * 8;
    const ushort* wG = sg.W + (size_t)lr * K + lc * 8;

    for (int k0 = 0; k0 < K; k0 += 32) {
        __syncthreads();
        *(short8*)&Al[lr][lc * 8] = *(const short8*)(aG + k0);
        *(short8*)&Bl[lr][lc * 8] = *(const short8*)(wG + k0);
        __syncthreads();
        short8 af0 = *(const short8*)&Al[mo + row16][quad * 8];
        short8 af1 = *(const short8*)&Al[mo + 16 + row16][quad * 8];
        short8 bf0 = *(const short8*)&Bl[no + row16][quad * 8];
        short8 bf1 = *(const short8*)&Bl[no + 16 + row16][quad * 8];
        acc[0][0] = __builtin_amdgcn_mfma_f32_16x16x32_bf16(af0, bf0, acc[0][0], 0, 0, 0);
        acc[0][1] = __builtin_amdgcn_mfma_f32_16x16x32_bf16(af0, bf1, acc[0][1], 0, 0, 0);
        acc[1][0] = __builtin_amdgcn_mfma_f32_16x16x32_bf16(af1, bf0, acc[1][0], 0, 0, 0);
        acc[1][1] = __builtin_amdgcn_mfma_f32_16x16x32_bf16(af1, bf1, acc[1][1], 0, 0, 0);
    }

#pragma unroll
    for (int mi = 0; mi < 2; ++mi)
#pragma unroll
        for (int ni = 0; ni < 2; ++ni) {
            const int col = no + ni * 16 + row16;   // local col 0..63
            const float bv = sg.bias[col];
            const int rowb = bm + mo + mi * 16 + quad * 4;   // aligned to 4
            if (sg.mode == 4) {
                const int b = rowb / NQ;
                const int mloc = rowb - b * NQ;
                ushort* base = (ushort*)sg.C
                    + ((size_t)b * 8 * NQ + (size_t)(col >> 5) * NQ) * 32 + (col & 31);
#pragma unroll
                for (int r = 0; r < 4; ++r)
                    base[(size_t)(mloc + r) * 32] = f2bf((acc[mi][ni][r] + bv) * sg.scale);
            } else if (sg.mode == 5) {
                const int b = rowb / NQ;
                const int mloc = rowb - b * NQ;    // mloc % 4 == 0
                ushort4 st;
                st.x = f2bf((acc[mi][ni][0] + bv) * sg.scale);
                st.y = f2bf((acc[mi][ni][1] + bv) * sg.scale);
                st.z = f2bf((acc[mi][ni][2] + bv) * sg.scale);
                st.w = f2bf((acc[mi][ni][3] + bv) * sg.scale);
                ushort* base = (ushort*)sg.C
                    + ((size_t)b * 8 * NQ + (size_t)(col >> 5) * NQ) * 32;
                *(ushort4*)(base + ((size_t)(mloc >> 2) * 32 + (col & 31)) * 4) = st;
            } else {
#pragma unroll
                for (int r = 0; r < 4; ++r) {
                    const int row = rowb + r;
                    float v = (acc[mi][ni][r] + bv) * sg.scale;
                    if (sg.mode == 0)
                        ((float*)sg.C)[(size_t)row * sg.ldc + col] = v;
                    else if (sg.mode == 1)
                        ((ushort*)sg.C)[(size_t)row * sg.ldc + col] = f2bf(fmaxf(v, 0.f));
                    else
                        ((ushort*)sg.C)[(size_t)row * sg.ldc + col] = f2bf(v);
                }
            }
        }
}

// ---------------------------------------------------------------------------
// MFMA flash self-attention — COALESCED LAYOUTS (TA-segment-count fix).
// Q/K head-major (b,h,q,32): K-fragment load = 1 contiguous KB per wave.
// V chunked-transpose (b,h,q>>2,d,q&3): PV B-fragment = 4x128B segs.
// S^T = K·Q^T (lane: q=lr, key=quad*4+r) -> exp in-register -> PV directly
// (P is already in 16x16x16 A-operand layout). Fixed-shift softmax.
// Grid (B*NHEAD, NQ/16); 4 waves split the 25 K-tiles; LDS combine at end.
// ---------------------------------------------------------------------------
#define FSHIFT 16.0f

__global__ __launch_bounds__(256) void attn_mfma(const ushort* __restrict__ Qh,
                                                 const ushort* __restrict__ Kh,
                                                 const ushort* __restrict__ Vt,
                                                 ushort* __restrict__ Oh)
{
    const int bh = blockIdx.x;
    const int h  = bh & 7, b = bh >> 3;
    const int q0 = blockIdx.y * 16;
    const int tid  = threadIdx.x;
    const int wave = tid >> 6, lane = tid & 63;
    const int lr   = lane & 15, quad = lane >> 4;

    __shared__ float Ol[4][16][33];   // per-wave partial O (q x d)
    __shared__ float Ll[4][16];       // per-wave partial lsum

    const ushort* Qb = Qh + (size_t)bh * NQ * 32;
    const ushort* Kb = Kh + (size_t)bh * NQ * 32;
    const ushort* Vb = Vt + (size_t)bh * NQ * 32;

    // Q fragment (B-operand of S^T MFMA): q = q0+lr, dims quad*8..+8
    const short8 qf = *(const short8*)(Qb + (size_t)(q0 + lr) * 32 + quad * 8);

    float lsum = 0.f;
    floatx4 accO[2] = {};
    const floatx4 zero = {0.f, 0.f, 0.f, 0.f};

    const int NT = NQ / 64;   // 25
    for (int t = wave; t < NT; t += 4) {
        const int k0 = t * 64;
#pragma unroll
        for (int cb = 0; cb < 4; ++cb) {
            // K fragment (A-operand): key = k0+cb*16+lr, dims quad*8..+8 — 1KB contiguous/wave
            const short8 kf = *(const short8*)(Kb + (size_t)(k0 + cb * 16 + lr) * 32 + quad * 8);
            const floatx4 st = __builtin_amdgcn_mfma_f32_16x16x32_bf16(kf, qf, zero, 0, 0, 0);
            // st[r]: q = lr, key = k0 + cb*16 + quad*4 + r
            // V fragments (B-operand 16x16x16): n=d, k=key — chunked layout, contiguous/lane-group
            const short4v v0 = *(const short4v*)(Vb + (size_t)(k0 + cb * 16 + quad * 4) * 32 + lr * 4);
            const short4v v1 = *(const short4v*)(Vb + (size_t)(k0 + cb * 16 + quad * 4) * 32 + 64 + lr * 4);
            short4v pf;
#pragma unroll
            for (int r = 0; r < 4; ++r) {
                const float p = EXP2F(fminf(st[r], 100.f) - FSHIFT);
                lsum += p;
                pf[r] = (short)f2bf_trunc(p);
            }
            accO[0] = MFMA16K16(pf, v0, accO[0]);
            accO[1] = MFMA16K16(pf, v1, accO[1]);
        }
    }

    // lsum: reduce across the 4 quads holding the same q = lr
    lsum += __shfl_xor(lsum, 16);
    lsum += __shfl_xor(lsum, 32);
    if (quad == 0) Ll[wave][lr] = lsum;
    // accO: q = quad*4+r, d = lr (+16)
#pragma unroll
    for (int r = 0; r < 4; ++r) {
        const int q = quad * 4 + r;
        Ol[wave][q][lr]      = accO[0][r];
        Ol[wave][q][16 + lr] = accO[1][r];
    }
    __syncthreads();

    // combine 4 wave-partials: 512 outputs, 2 per thread
#pragma unroll
    for (int i = 0; i < 2; ++i) {
        const int idx = tid + i * 256;
        const int q = idx >> 5, d = idx & 31;
        const float o  = Ol[0][q][d] + Ol[1][q][d] + Ol[2][q][d] + Ol[3][q][d];
        const float lt = Ll[0][q] + Ll[1][q] + Ll[2][q] + Ll[3][q];
        Oh[(size_t)(b * NQ + q0 + q) * 256 + h * 32 + d] = f2bf(o / lt);
    }
}

// ---------------------------------------------------------------------------
// Segmented fp32 -> bf16 conversion (weights + src), one launch.
// ---------------------------------------------------------------------------
struct CvtSeg { const float* in; ushort* out; int n4; };
struct CvtArgs { CvtSeg seg[11]; };

__global__ __launch_bounds__(256) void convert_kernel(CvtArgs args)
{
    const CvtSeg sg = args.seg[blockIdx.y];
    const int i = blockIdx.x * 256 + threadIdx.x;
    if (i < sg.n4) {
        float4 v = ((const float4*)sg.in)[i];
        ushort4 o;
        o.x = f2bf(v.x); o.y = f2bf(v.y); o.z = f2bf(v.z); o.w = f2bf(v.w);
        ((ushort4*)sg.out)[i] = o;
    }
}

// out = tgt (fp32), out_h = bf16(tgt), qadd_h = bf16(tgt + qpos)
__global__ __launch_bounds__(256) void init_out_kernel(const float* __restrict__ tgt,
                                                       const float* __restrict__ qpos,
                                                       float* __restrict__ out,
                                                       ushort* __restrict__ out_h,
                                                       ushort* __restrict__ qadd_h, int n4)
{
    const int i = blockIdx.x * 256 + threadIdx.x;
    if (i < n4) {
        float4 v = ((const float4*)tgt)[i];
        float4 p = ((const float4*)qpos)[i];
        ((float4*)out)[i] = v;
        ushort4 o, qa;
        o.x = f2bf(v.x); o.y = f2bf(v.y); o.z = f2bf(v.z); o.w = f2bf(v.w);
        qa.x = f2bf(v.x + p.x); qa.y = f2bf(v.y + p.y);
        qa.z = f2bf(v.z + p.z); qa.w = f2bf(v.w + p.w);
        ((ushort4*)out_h)[i] = o;
        ((ushort4*)qadd_h)[i] = qa;
    }
}

// ---------------------------------------------------------------------------
// Fused residual + LayerNorm -> out fp32, out_h bf16, qadd_h = bf16(ln + qpos).
// One block per row. In-place safe.
// ---------------------------------------------------------------------------
__global__ __launch_bounds__(256) void residual_ln_kernel(const float* __restrict__ x,
                                                          const float* __restrict__ t2,
                                                          const float* __restrict__ g,
                                                          const float* __restrict__ bt,
                                                          const float* __restrict__ qpos,
                                                          float* __restrict__ outp,
                                                          ushort* __restrict__ outp_h,
                                                          ushort* __restrict__ qadd_h)
{
    const int row = blockIdx.x;
    const int c = threadIdx.x;
    const size_t idx = (size_t)row * D_MODEL + c;
    float v = x[idx] + t2[idx];

    float s = v, s2 = v * v;
#pragma unroll
    for (int off = 32; off; off >>= 1) {
        s  += __shfl_xor(s,  off);
        s2 += __shfl_xor(s2, off);
    }
    __shared__ float ws[4], ws2[4];
    const int wid = c >> 6;
    if ((c & 63) == 0) { ws[wid] = s; ws2[wid] = s2; }
    __syncthreads();
    const float tot  = ws[0] + ws[1] + ws[2] + ws[3];
    const float tot2 = ws2[0] + ws2[1] + ws2[2] + ws2[3];
    const float mu  = tot * (1.f / 256.f);
    const float var = tot2 * (1.f / 256.f) - mu * mu;
    const float r = (v - mu) * rsqrtf(var + 1e-5f) * g[c] + bt[c];
    outp[idx] = r;
    outp_h[idx] = f2bf(r);
    qadd_h[idx] = f2bf(r + qpos[idx]);
}

// ---------------------------------------------------------------------------
// Deformable sampling with inline softmax over the 16 attention weights.
// Block per (b,q); thread = (head h = tid>>5, chan c = tid&31).
// ---------------------------------------------------------------------------
__global__ __launch_bounds__(256) void sample_kernel(const ushort* __restrict__ value,
                                                     const float* __restrict__ off,
                                                     const float* __restrict__ aw,
                                                     const float* __restrict__ ref,
                                                     ushort* __restrict__ outp_h)
{
    const int bq = blockIdx.x;
    const int b  = bq / NQ;
    const int h  = threadIdx.x >> 5;
    const int c  = threadIdx.x & 31;

    const float* offrow = off + (size_t)bq * 256 + h * 32;
    const float* awrow  = aw  + (size_t)bq * 128 + h * 16;
    const float* refrow = ref + (size_t)bq * 8;

    float w16[16];
    {
        float mx = -1e30f;
#pragma unroll
        for (int i = 0; i < 16; ++i) { w16[i] = awrow[i]; mx = fmaxf(mx, w16[i]); }
        float sum = 0.f;
#pragma unroll
        for (int i = 0; i < 16; ++i) { w16[i] = __expf(w16[i] - mx); sum += w16[i]; }
        const float inv = 1.f / sum;
#pragma unroll
        for (int i = 0; i < 16; ++i) w16[i] *= inv;
    }

    const int HL[4]  = {64, 32, 16, 8};
    const int WLv[4] = {64, 32, 16, 8};
    const int S0[4]  = {0, 4096, 5120, 5376};

    float acc = 0.f;
#pragma unroll
    for (int l = 0; l < 4; ++l) {
        const int Hl = HL[l], Wl = WLv[l];
        const float rx = refrow[l * 2 + 0];
        const float ry = refrow[l * 2 + 1];
        const size_t lvl_base = ((size_t)b * S_TOTAL + S0[l]);
#pragma unroll
        for (int p = 0; p < 4; ++p) {
            const float ox = offrow[l * 8 + p * 2 + 0];
            const float oy = offrow[l * 8 + p * 2 + 1];
            const float w  = w16[l * 4 + p];
            const float locx = rx + ox / (float)Wl;
            const float locy = ry + oy / (float)Hl;
            const float x = locx * (float)Wl - 0.5f;
            const float y = locy * (float)Hl - 0.5f;
            const float x0f = floorf(x), y0f = floorf(y);
            const float wx1 = x - x0f, wy1 = y - y0f;
            const int x0 = (int)x0f, y0 = (int)y0f;
#pragma unroll
            for (int dy = 0; dy < 2; ++dy) {
                const int yi = y0 + dy;
                const float wy = dy ? wy1 : (1.f - wy1);
                const bool vy = (yi >= 0) && (yi <= Hl - 1);
                const int yc = min(max(yi, 0), Hl - 1);
#pragma unroll
                for (int dx = 0; dx < 2; ++dx) {
                    const int xi = x0 + dx;
                    const float wx = dx ? wx1 : (1.f - wx1);
                    const bool vx = (xi >= 0) && (xi <= Wl - 1);
                    const int xc = min(max(xi, 0), Wl - 1);
                    const float gv = bf2f(value[((lvl_base + (size_t)yc * Wl + xc)) * 256 + h * 32 + c]);
                    acc += (vx && vy) ? gv * (wx * wy * w) : 0.f;
                }
            }
        }
    }
    outp_h[(size_t)bq * D_MODEL + h * 32 + c] = f2bf(acc);
}

// ---------------------------------------------------------------------------
// Host-side orchestration
// ---------------------------------------------------------------------------
extern "C" void kernel_launch(void* const* d_in, const int* in_sizes, int n_in,
                              void* d_out, int out_size, void* d_ws, size_t ws_size,
                              hipStream_t stream)
{
    const float* tgt  = (const float*)d_in[0];
    const float* qpos = (const float*)d_in[1];
    const float* refp = (const float*)d_in[2];
    const float* src  = (const float*)d_in[3];

    // ---- workspace carve-up ----
    float* bufT   = (float*)d_ws;                   // 819200 (GEMM fp32 out pre-LN)
    float* bufOff = bufT   + ROW_ELEMS;             // 819200
    float* bufAw  = bufOff + ROW_ELEMS;             // 409600

    ushort* out_h   = (ushort*)(bufAw + (size_t)M_Q * 128);
    ushort* qadd_h  = out_h   + ROW_ELEMS;
    ushort* bufX_h  = qadd_h  + ROW_ELEMS;          // attn-out / sample-out
    ushort* bufQh   = bufX_h  + ROW_ELEMS;          // head-major Q (b,h,q,32)
    ushort* bufKh   = bufQh   + ROW_ELEMS;          // head-major K
    ushort* bufVt   = bufKh   + ROW_ELEMS;          // V chunked-transpose
    ushort* bufF_h  = bufVt   + ROW_ELEMS;          // 3276800 ffn hidden
    ushort* bufVal  = bufF_h  + (size_t)M_Q * D_FFN;   // 2785280 deform value
    ushort* src_h   = bufVal  + (size_t)M_V * D_MODEL; // 2785280
    ushort* wpool   = src_h   + (size_t)M_V * D_MODEL;

    ushort* wq_h    = wpool;
    ushort* wk_h    = wq_h    + 393216;
    ushort* wv_h    = wk_h    + 393216;
    ushort* wo_h    = wv_h    + 393216;
    ushort* woff_h  = wo_h    + 393216;
    ushort* wattn_h = woff_h  + 393216;
    ushort* wval_h  = wattn_h + 196608;
    ushort* wout_h  = wval_h  + 393216;
    ushort* w1_h    = wout_h  + 393216;
    ushort* w2_h    = w1_h    + 1572864;

    float* out = (float*)d_out;

    // ---- conversions ----
    CvtArgs ca;
    ca.seg[0]  = { src,                    src_h,   (int)((size_t)M_V * D_MODEL / 4) };
    ca.seg[1]  = { (const float*)d_in[4],  wq_h,    393216 / 4 };
    ca.seg[2]  = { (const float*)d_in[6],  wk_h,    393216 / 4 };
    ca.seg[3]  = { (const float*)d_in[8],  wv_h,    393216 / 4 };
    ca.seg[4]  = { (const float*)d_in[10], wo_h,    393216 / 4 };
    ca.seg[5]  = { (const float*)d_in[14], woff_h,  393216 / 4 };
    ca.seg[6]  = { (const float*)d_in[16], wattn_h, 196608 / 4 };
    ca.seg[7]  = { (const float*)d_in[18], wval_h,  393216 / 4 };
    ca.seg[8]  = { (const float*)d_in[20], wout_h,  393216 / 4 };
    ca.seg[9]  = { (const float*)d_in[24], w1_h,    1572864 / 4 };
    ca.seg[10] = { (const float*)d_in[26], w2_h,    1572864 / 4 };
    convert_kernel<<<dim3(2720, 11), 256, 0, stream>>>(ca);

    init_out_kernel<<<800, 256, 0, stream>>>(tgt, qpos, out, out_h, qadd_h, (int)(ROW_ELEMS / 4));

    // Q pre-scale: log2(e)/sqrt(32) so attention computes exp2 directly
    const float QSCALE = 0.1767766952966369f * 1.4426950408889634f;
    const int MB_Q = M_Q / 64;   // 50
    const int MB_V = M_V / 64;   // 170

    for (int l = 0; l < NUM_LAYERS; ++l) {
        const float* sa_b_q    = (const float*)d_in[5]  + (size_t)l * 256;
        const float* sa_b_k    = (const float*)d_in[7]  + (size_t)l * 256;
        const float* sa_b_v    = (const float*)d_in[9]  + (size_t)l * 256;
        const float* sa_b_o    = (const float*)d_in[11] + (size_t)l * 256;
        const float* ln2_g     = (const float*)d_in[12] + (size_t)l * 256;
        const float* ln2_b     = (const float*)d_in[13] + (size_t)l * 256;
        const float* ca_b_off  = (const float*)d_in[15] + (size_t)l * 256;
        const float* ca_b_attn = (const float*)d_in[17] + (size_t)l * 128;
        const float* ca_b_val  = (const float*)d_in[19] + (size_t)l * 256;
        const float* ca_b_out  = (const float*)d_in[21] + (size_t)l * 256;
        const float* ln1_g     = (const float*)d_in[22] + (size_t)l * 256;
        const float* ln1_b     = (const float*)d_in[23] + (size_t)l * 256;
        const float* ffn_b1    = (const float*)d_in[25] + (size_t)l * 1024;
        const float* ffn_b2    = (const float*)d_in[27] + (size_t)l * 256;
        const float* ln3_g     = (const float*)d_in[28] + (size_t)l * 256;
        const float* ln3_b     = (const float*)d_in[29] + (size_t)l * 256;

        const ushort* wq = wq_h    + (size_t)l * 65536;
        const ushort* wk = wk_h    + (size_t)l * 65536;
        const ushort* wv = wv_h    + (size_t)l * 65536;
        const ushort* wo = wo_h    + (size_t)l * 65536;
        const ushort* wf = woff_h  + (size_t)l * 65536;
        const ushort* wa = wattn_h + (size_t)l * 32768;
        const ushort* wl = wval_h  + (size_t)l * 65536;
        const ushort* wu = wout_h  + (size_t)l * 65536;
        const ushort* w1 = w1_h    + (size_t)l * 262144;
        const ushort* w2 = w2_h    + (size_t)l * 262144;

        GArgs ga;

        // ---- QKV projections (head-major / chunked-V) + deform value proj ----
        for (int i = 0; i < 4; ++i) {
            // cols [i*64, i*64+64) = heads 2i, 2i+1 -> C pre-offset 2i*NQ*32 ushorts
            ga.s[i]      = { qadd_h, wq + (size_t)i * 64 * 256, sa_b_q + i * 64,
                             bufQh + (size_t)(2 * i) * NQ * 32, 0, 4, MB_Q, QSCALE };
            ga.s[4 + i]  = { qadd_h, wk + (size_t)i * 64 * 256, sa_b_k + i * 64,
                             bufKh + (size_t)(2 * i) * NQ * 32, 0, 4, MB_Q, 1.f };
            ga.s[8 + i]  = { out_h,  wv + (size_t)i * 64 * 256, sa_b_v + i * 64,
                             bufVt + (size_t)(2 * i) * NQ * 32, 0, 5, MB_Q, 1.f };
            ga.s[12 + i] = { src_h,  wl + (size_t)i * 64 * 256, ca_b_val + i * 64,
                             bufVal + i * 64, 256, 2, MB_V, 1.f };
        }
        gemm_multi<<<dim3(MB_V, 16), 256, 0, stream>>>(ga, 256);

        attn_mfma<<<dim3(16, NQ / 16), 256, 0, stream>>>(bufQh, bufKh, bufVt, bufX_h);

        for (int i = 0; i < 4; ++i)
            ga.s[i] = { bufX_h, wo + (size_t)i * 64 * 256, sa_b_o + i * 64, bufT + i * 64, 256, 0, MB_Q, 1.f };
        gemm_multi<<<dim3(MB_Q, 4), 256, 0, stream>>>(ga, 256);

        residual_ln_kernel<<<M_Q, 256, 0, stream>>>(out, bufT, ln2_g, ln2_b, qpos, out, out_h, qadd_h);

        // ---- Deformable cross-attention ----
        for (int i = 0; i < 4; ++i)
            ga.s[i] = { qadd_h, wf + (size_t)i * 64 * 256, ca_b_off + i * 64, bufOff + i * 64, 256, 0, MB_Q, 1.f };
        for (int i = 0; i < 2; ++i)
            ga.s[4 + i] = { qadd_h, wa + (size_t)i * 64 * 256, ca_b_attn + i * 64, bufAw + i * 64, 128, 0, MB_Q, 1.f };
        gemm_multi<<<dim3(MB_Q, 6), 256, 0, stream>>>(ga, 256);

        sample_kernel<<<M_Q, 256, 0, stream>>>(bufVal, bufOff, bufAw, refp, bufX_h);

        for (int i = 0; i < 4; ++i)
            ga.s[i] = { bufX_h, wu + (size_t)i * 64 * 256, ca_b_out + i * 64, bufT + i * 64, 256, 0, MB_Q, 1.f };
        gemm_multi<<<dim3(MB_Q, 4), 256, 0, stream>>>(ga, 256);

        residual_ln_kernel<<<M_Q, 256, 0, stream>>>(out, bufT, ln1_g, ln1_b, qpos, out, out_h, qadd_h);

        // ---- FFN ----
        for (int i = 0; i < 16; ++i)
            ga.s[i] = { out_h, w1 + (size_t)i * 64 * 256, ffn_b1 + i * 64, bufF_h + i * 64, 1024, 1, MB_Q, 1.f };
        gemm_multi<<<dim3(MB_Q, 16), 256, 0, stream>>>(ga, 256);

        for (int i = 0; i < 4; ++i)
            ga.s[i] = { bufF_h, w2 + (size_t)i * 64 * 1024, ffn_b2 + i * 64, bufT + i * 64, 256, 0, MB_Q, 1.f };
        gemm_multi<<<dim3(MB_Q, 4), 256, 0, stream>>>(ga, 1024);

        residual_ln_kernel<<<M_Q, 256, 0, stream>>>(out, bufT, ln3_g, ln3_b, qpos, out, out_h, qadd_h);
    }

    (void)in_sizes; (void)n_in; (void)out_size; (void)ws_size;
}

// Round 11
// 873.825 us; speedup vs baseline: 1.4933x; 1.0337x over previous
//
#include <hip/hip_runtime.h>

// Problem constants (fixed by the reference)
#define D_MODEL   256
#define NQ        1600
#define BATCH     2
#define NHEAD     8
#define HDIM      32
#define S_TOTAL   5440
#define D_FFN     1024
#define NUM_LAYERS 6

#define M_Q   (BATCH * NQ)       // 3200
#define M_V   (BATCH * S_TOTAL)  // 10880
#define ROW_ELEMS ((size_t)M_Q * D_MODEL)   // 819200

using short8  = __attribute__((ext_vector_type(8))) short;
using short4v = __attribute__((ext_vector_type(4))) short;
using floatx4 = __attribute__((ext_vector_type(4))) float;

// 16x16x16 bf16 MFMA builtin name differs across LLVM versions
#if __has_builtin(__builtin_amdgcn_mfma_f32_16x16x16_bf16)
  #define MFMA16K16(a,b,c) __builtin_amdgcn_mfma_f32_16x16x16_bf16((a),(b),(c),0,0,0)
#else
  #define MFMA16K16(a,b,c) __builtin_amdgcn_mfma_f32_16x16x16bf16_1k((a),(b),(c),0,0,0)
#endif

#if __has_builtin(__builtin_amdgcn_exp2f)
  #define EXP2F(x) __builtin_amdgcn_exp2f(x)
#else
  #define EXP2F(x) exp2f(x)
#endif

__device__ __forceinline__ ushort f2bf(float f) {
    union { float f; unsigned u; } x; x.f = f;
    unsigned r = (x.u + 0x7fffu + ((x.u >> 16) & 1u)) >> 16;
    return (ushort)r;
}
__device__ __forceinline__ ushort f2bf_trunc(float f) {
    union { float f; unsigned u; } x; x.f = f;
    return (ushort)(x.u >> 16);
}
__device__ __forceinline__ float bf2f(ushort b) {
    union { unsigned u; float f; } x; x.u = ((unsigned)b) << 16;
    return x.f;
}

// ---------------------------------------------------------------------------
// Segmented bf16 MFMA GEMM (LDS-staged). Each bn-block (64 cols) descriptor:
//   mode 0: fp32 store          1: relu+bf16      2: bf16
//   mode 4: head-major bf16 (b, h=gcol>>5, q, d=gcol&31)  [C pre-offset by h0*NQ*32]
//   mode 5: V chunked-transpose (b, h, q>>2, d, q&3)      [C pre-offset by h0*NQ*32]
// mblk: valid 64-row blocks for this segment. 64x64 tile, BK=32, 4 waves.
// ---------------------------------------------------------------------------
struct GSeg {
    const ushort* A;
    const ushort* W;      // pre-offset to this 64-col block
    const float*  bias;   // pre-offset
    void*         C;      // col-offset pre-applied (modes 0-2); h0*NQ*32 for 4/5
    int           ldc;
    int           mode;
    int           mblk;
    float         scale;
};
struct GArgs { GSeg s[24]; };

__global__ __launch_bounds__(256) void gemm_multi(GArgs args, int K)
{
    const GSeg sg = args.s[blockIdx.y];
    if ((int)blockIdx.x >= sg.mblk) return;
    __shared__ ushort Al[64][40];
    __shared__ ushort Bl[64][40];
    const int tid  = threadIdx.x;
    const int bm   = blockIdx.x * 64;
    const int lr   = tid >> 2;
    const int lc   = tid & 3;
    const int wave = tid >> 6;
    const int lane = tid & 63;
    const int mo   = (wave & 1) * 32;
    const int no   = (wave >> 1) * 32;
    const int row16 = lane & 15;
    const int quad  = lane >> 4;

    floatx4 acc[2][2] = {};

    const ushort* aG = sg.A + (size_t)(bm + lr) * K + lc * 8;
    const ushort* wG = sg.W + (size_t)lr * K + lc * 8;

    for (int k0 = 0; k0 < K; k0 += 32) {
        __syncthreads();
        *(short8*)&Al[lr][lc * 8] = *(const short8*)(aG + k0);
        *(short8*)&Bl[lr][lc * 8] = *(const short8*)(wG + k0);
        __syncthreads();
        short8 af0 = *(const short8*)&Al[mo + row16][quad * 8];
        short8 af1 = *(const short8*)&Al[mo + 16 + row16][quad * 8];
        short8 bf0 = *(const short8*)&Bl[no + row16][quad * 8];
        short8 bf1 = *(const short8*)&Bl[no + 16 + row16][quad * 8];
        acc[0][0] = __builtin_amdgcn_mfma_f32_16x16x32_bf16(af0, bf0, acc[0][0], 0, 0, 0);
        acc[0][1] = __builtin_amdgcn_mfma_f32_16x16x32_bf16(af0, bf1, acc[0][1], 0, 0, 0);
        acc[1][0] = __builtin_amdgcn_mfma_f32_16x16x32_bf16(af1, bf0, acc[1][0], 0, 0, 0);
        acc[1][1] = __builtin_amdgcn_mfma_f32_16x16x32_bf16(af1, bf1, acc[1][1], 0, 0, 0);
    }

#pragma unroll
    for (int mi = 0; mi < 2; ++mi)
#pragma unroll
        for (int ni = 0; ni < 2; ++ni) {
            const int col = no + ni * 16 + row16;   // local col 0..63
            const float bv = sg.bias[col];
            const int rowb = bm + mo + mi * 16 + quad * 4;   // aligned to 4
            if (sg.mode == 4) {
                const int b = rowb / NQ;
                const int mloc = rowb - b * NQ;
                ushort* base = (ushort*)sg.C
                    + ((size_t)b * 8 * NQ + (size_t)(col >> 5) * NQ) * 32 + (col & 31);
#pragma unroll
                for (int r = 0; r < 4; ++r)
                    base[(size_t)(mloc + r) * 32] = f2bf((acc[mi][ni][r] + bv) * sg.scale);
            } else if (sg.mode == 5) {
                const int b = rowb / NQ;
                const int mloc = rowb - b * NQ;    // mloc % 4 == 0
                ushort4 st;
                st.x = f2bf((acc[mi][ni][0] + bv) * sg.scale);
                st.y = f2bf((acc[mi][ni][1] + bv) * sg.scale);
                st.z = f2bf((acc[mi][ni][2] + bv) * sg.scale);
                st.w = f2bf((acc[mi][ni][3] + bv) * sg.scale);
                ushort* base = (ushort*)sg.C
                    + ((size_t)b * 8 * NQ + (size_t)(col >> 5) * NQ) * 32;
                *(ushort4*)(base + ((size_t)(mloc >> 2) * 32 + (col & 31)) * 4) = st;
            } else {
#pragma unroll
                for (int r = 0; r < 4; ++r) {
                    const int row = rowb + r;
                    float v = (acc[mi][ni][r] + bv) * sg.scale;
                    if (sg.mode == 0)
                        ((float*)sg.C)[(size_t)row * sg.ldc + col] = v;
                    else if (sg.mode == 1)
                        ((ushort*)sg.C)[(size_t)row * sg.ldc + col] = f2bf(fmaxf(v, 0.f));
                    else
                        ((ushort*)sg.C)[(size_t)row * sg.ldc + col] = f2bf(v);
                }
            }
        }
}

// ---------------------------------------------------------------------------
// MFMA flash self-attention — coalesced layouts, 32 QUERIES PER BLOCK
// (K/V reads amortized over 2 q-tiles). Q/K head-major (b,h,q,32);
// V chunked-transpose (b,h,q>>2,d,q&3). S^T = K·Q^T -> exp in-register ->
// PV directly (P already in 16x16x16 A-operand layout). Fixed-shift softmax.
// Grid (B*NHEAD, NQ/32); 4 waves split the 25 K-tiles; LDS combine at end.
// ---------------------------------------------------------------------------
#define FSHIFT 16.0f

__global__ __launch_bounds__(256) void attn_mfma(const ushort* __restrict__ Qh,
                                                 const ushort* __restrict__ Kh,
                                                 const ushort* __restrict__ Vt,
                                                 ushort* __restrict__ Oh)
{
    const int bh = blockIdx.x;
    const int h  = bh & 7, b = bh >> 3;
    const int q0 = blockIdx.y * 32;
    const int tid  = threadIdx.x;
    const int wave = tid >> 6, lane = tid & 63;
    const int lr   = lane & 15, quad = lane >> 4;

    __shared__ float Ol[4][32][33];   // per-wave partial O (q x d)
    __shared__ float Ll[4][32];       // per-wave partial lsum

    const ushort* Qb = Qh + (size_t)bh * NQ * 32;
    const ushort* Kb = Kh + (size_t)bh * NQ * 32;
    const ushort* Vb = Vt + (size_t)bh * NQ * 32;

    // Q fragments (B-operand of S^T MFMA): q = q0+lr / q0+16+lr
    const short8 qfA = *(const short8*)(Qb + (size_t)(q0 + lr) * 32 + quad * 8);
    const short8 qfB = *(const short8*)(Qb + (size_t)(q0 + 16 + lr) * 32 + quad * 8);

    float lsumA = 0.f, lsumB = 0.f;
    floatx4 accOA[2] = {}, accOB[2] = {};
    const floatx4 zero = {0.f, 0.f, 0.f, 0.f};

    const int NT = NQ / 64;   // 25
    for (int t = wave; t < NT; t += 4) {
        const int k0 = t * 64;
#pragma unroll
        for (int cb = 0; cb < 4; ++cb) {
            // K fragment (A-operand): key = k0+cb*16+lr — 1KB contiguous per wave
            const short8 kf = *(const short8*)(Kb + (size_t)(k0 + cb * 16 + lr) * 32 + quad * 8);
            const floatx4 stA = __builtin_amdgcn_mfma_f32_16x16x32_bf16(kf, qfA, zero, 0, 0, 0);
            const floatx4 stB = __builtin_amdgcn_mfma_f32_16x16x32_bf16(kf, qfB, zero, 0, 0, 0);
            // V fragments (B-operand 16x16x16): n=d, k=key — chunked layout
            const short4v v0 = *(const short4v*)(Vb + (size_t)(k0 + cb * 16 + quad * 4) * 32 + lr * 4);
            const short4v v1 = *(const short4v*)(Vb + (size_t)(k0 + cb * 16 + quad * 4) * 32 + 64 + lr * 4);
            short4v pfA, pfB;
#pragma unroll
            for (int r = 0; r < 4; ++r) {
                const float pA = EXP2F(fminf(stA[r], 100.f) - FSHIFT);
                const float pB = EXP2F(fminf(stB[r], 100.f) - FSHIFT);
                lsumA += pA; lsumB += pB;
                pfA[r] = (short)f2bf_trunc(pA);
                pfB[r] = (short)f2bf_trunc(pB);
            }
            accOA[0] = MFMA16K16(pfA, v0, accOA[0]);
            accOA[1] = MFMA16K16(pfA, v1, accOA[1]);
            accOB[0] = MFMA16K16(pfB, v0, accOB[0]);
            accOB[1] = MFMA16K16(pfB, v1, accOB[1]);
        }
    }

    // lsum: reduce across the 4 quads holding the same q = lr
    lsumA += __shfl_xor(lsumA, 16);  lsumB += __shfl_xor(lsumB, 16);
    lsumA += __shfl_xor(lsumA, 32);  lsumB += __shfl_xor(lsumB, 32);
    if (quad == 0) { Ll[wave][lr] = lsumA; Ll[wave][16 + lr] = lsumB; }
    // accO: q = quad*4+r (A) / 16+quad*4+r (B), d = lr (+16)
#pragma unroll
    for (int r = 0; r < 4; ++r) {
        const int q = quad * 4 + r;
        Ol[wave][q][lr]           = accOA[0][r];
        Ol[wave][q][16 + lr]      = accOA[1][r];
        Ol[wave][16 + q][lr]      = accOB[0][r];
        Ol[wave][16 + q][16 + lr] = accOB[1][r];
    }
    __syncthreads();

    // combine 4 wave-partials: 1024 outputs, 4 per thread
#pragma unroll
    for (int i = 0; i < 4; ++i) {
        const int idx = tid + i * 256;
        const int q = idx >> 5, d = idx & 31;
        const float o  = Ol[0][q][d] + Ol[1][q][d] + Ol[2][q][d] + Ol[3][q][d];
        const float lt = Ll[0][q] + Ll[1][q] + Ll[2][q] + Ll[3][q];
        Oh[(size_t)(b * NQ + q0 + q) * 256 + h * 32 + d] = f2bf(o / lt);
    }
}

// ---------------------------------------------------------------------------
// Segmented fp32 -> bf16 conversion (weights + src), one launch.
// ---------------------------------------------------------------------------
struct CvtSeg { const float* in; ushort* out; int n4; };
struct CvtArgs { CvtSeg seg[11]; };

__global__ __launch_bounds__(256) void convert_kernel(CvtArgs args)
{
    const CvtSeg sg = args.seg[blockIdx.y];
    const int i = blockIdx.x * 256 + threadIdx.x;
    if (i < sg.n4) {
        float4 v = ((const float4*)sg.in)[i];
        ushort4 o;
        o.x = f2bf(v.x); o.y = f2bf(v.y); o.z = f2bf(v.z); o.w = f2bf(v.w);
        ((ushort4*)sg.out)[i] = o;
    }
}

// out = tgt (fp32), out_h = bf16(tgt), qadd_h = bf16(tgt + qpos)
__global__ __launch_bounds__(256) void init_out_kernel(const float* __restrict__ tgt,
                                                       const float* __restrict__ qpos,
                                                       float* __restrict__ out,
                                                       ushort* __restrict__ out_h,
                                                       ushort* __restrict__ qadd_h, int n4)
{
    const int i = blockIdx.x * 256 + threadIdx.x;
    if (i < n4) {
        float4 v = ((const float4*)tgt)[i];
        float4 p = ((const float4*)qpos)[i];
        ((float4*)out)[i] = v;
        ushort4 o, qa;
        o.x = f2bf(v.x); o.y = f2bf(v.y); o.z = f2bf(v.z); o.w = f2bf(v.w);
        qa.x = f2bf(v.x + p.x); qa.y = f2bf(v.y + p.y);
        qa.z = f2bf(v.z + p.z); qa.w = f2bf(v.w + p.w);
        ((ushort4*)out_h)[i] = o;
        ((ushort4*)qadd_h)[i] = qa;
    }
}

// ---------------------------------------------------------------------------
// Fused residual + LayerNorm -> out fp32, out_h bf16, qadd_h = bf16(ln + qpos).
// One block per row. In-place safe.
// ---------------------------------------------------------------------------
__global__ __launch_bounds__(256) void residual_ln_kernel(const float* __restrict__ x,
                                                          const float* __restrict__ t2,
                                                          const float* __restrict__ g,
                                                          const float* __restrict__ bt,
                                                          const float* __restrict__ qpos,
                                                          float* __restrict__ outp,
                                                          ushort* __restrict__ outp_h,
                                                          ushort* __restrict__ qadd_h)
{
    const int row = blockIdx.x;
    const int c = threadIdx.x;
    const size_t idx = (size_t)row * D_MODEL + c;
    float v = x[idx] + t2[idx];

    float s = v, s2 = v * v;
#pragma unroll
    for (int off = 32; off; off >>= 1) {
        s  += __shfl_xor(s,  off);
        s2 += __shfl_xor(s2, off);
    }
    __shared__ float ws[4], ws2[4];
    const int wid = c >> 6;
    if ((c & 63) == 0) { ws[wid] = s; ws2[wid] = s2; }
    __syncthreads();
    const float tot  = ws[0] + ws[1] + ws[2] + ws[3];
    const float tot2 = ws2[0] + ws2[1] + ws2[2] + ws2[3];
    const float mu  = tot * (1.f / 256.f);
    const float var = tot2 * (1.f / 256.f) - mu * mu;
    const float r = (v - mu) * rsqrtf(var + 1e-5f) * g[c] + bt[c];
    outp[idx] = r;
    outp_h[idx] = f2bf(r);
    qadd_h[idx] = f2bf(r + qpos[idx]);
}

// ---------------------------------------------------------------------------
// Deformable sampling with inline softmax over the 16 attention weights.
// Block per (b,q); thread = (head h = tid>>5, chan c = tid&31).
// ---------------------------------------------------------------------------
__global__ __launch_bounds__(256) void sample_kernel(const ushort* __restrict__ value,
                                                     const float* __restrict__ off,
                                                     const float* __restrict__ aw,
                                                     const float* __restrict__ ref,
                                                     ushort* __restrict__ outp_h)
{
    const int bq = blockIdx.x;
    const int b  = bq / NQ;
    const int h  = threadIdx.x >> 5;
    const int c  = threadIdx.x & 31;

    const float* offrow = off + (size_t)bq * 256 + h * 32;
    const float* awrow  = aw  + (size_t)bq * 128 + h * 16;
    const float* refrow = ref + (size_t)bq * 8;

    float w16[16];
    {
        float mx = -1e30f;
#pragma unroll
        for (int i = 0; i < 16; ++i) { w16[i] = awrow[i]; mx = fmaxf(mx, w16[i]); }
        float sum = 0.f;
#pragma unroll
        for (int i = 0; i < 16; ++i) { w16[i] = __expf(w16[i] - mx); sum += w16[i]; }
        const float inv = 1.f / sum;
#pragma unroll
        for (int i = 0; i < 16; ++i) w16[i] *= inv;
    }

    const int HL[4]  = {64, 32, 16, 8};
    const int WLv[4] = {64, 32, 16, 8};
    const int S0[4]  = {0, 4096, 5120, 5376};

    float acc = 0.f;
#pragma unroll
    for (int l = 0; l < 4; ++l) {
        const int Hl = HL[l], Wl = WLv[l];
        const float rx = refrow[l * 2 + 0];
        const float ry = refrow[l * 2 + 1];
        const size_t lvl_base = ((size_t)b * S_TOTAL + S0[l]);
#pragma unroll
        for (int p = 0; p < 4; ++p) {
            const float ox = offrow[l * 8 + p * 2 + 0];
            const float oy = offrow[l * 8 + p * 2 + 1];
            const float w  = w16[l * 4 + p];
            const float locx = rx + ox / (float)Wl;
            const float locy = ry + oy / (float)Hl;
            const float x = locx * (float)Wl - 0.5f;
            const float y = locy * (float)Hl - 0.5f;
            const float x0f = floorf(x), y0f = floorf(y);
            const float wx1 = x - x0f, wy1 = y - y0f;
            const int x0 = (int)x0f, y0 = (int)y0f;
#pragma unroll
            for (int dy = 0; dy < 2; ++dy) {
                const int yi = y0 + dy;
                const float wy = dy ? wy1 : (1.f - wy1);
                const bool vy = (yi >= 0) && (yi <= Hl - 1);
                const int yc = min(max(yi, 0), Hl - 1);
#pragma unroll
                for (int dx = 0; dx < 2; ++dx) {
                    const int xi = x0 + dx;
                    const float wx = dx ? wx1 : (1.f - wx1);
                    const bool vx = (xi >= 0) && (xi <= Wl - 1);
                    const int xc = min(max(xi, 0), Wl - 1);
                    const float gv = bf2f(value[((lvl_base + (size_t)yc * Wl + xc)) * 256 + h * 32 + c]);
                    acc += (vx && vy) ? gv * (wx * wy * w) : 0.f;
                }
            }
        }
    }
    outp_h[(size_t)bq * D_MODEL + h * 32 + c] = f2bf(acc);
}

// ---------------------------------------------------------------------------
// Host-side orchestration
// ---------------------------------------------------------------------------
extern "C" void kernel_launch(void* const* d_in, const int* in_sizes, int n_in,
                              void* d_out, int out_size, void* d_ws, size_t ws_size,
                              hipStream_t stream)
{
    const float* tgt  = (const float*)d_in[0];
    const float* qpos = (const float*)d_in[1];
    const float* refp = (const float*)d_in[2];
    const float* src  = (const float*)d_in[3];

    // ---- workspace carve-up ----
    float* bufT   = (float*)d_ws;                   // 819200 (GEMM fp32 out pre-LN)
    float* bufOff = bufT   + ROW_ELEMS;             // 819200
    float* bufAw  = bufOff + ROW_ELEMS;             // 409600

    ushort* out_h   = (ushort*)(bufAw + (size_t)M_Q * 128);
    ushort* qadd_h  = out_h   + ROW_ELEMS;
    ushort* bufX_h  = qadd_h  + ROW_ELEMS;          // attn-out / sample-out
    ushort* bufQh   = bufX_h  + ROW_ELEMS;          // head-major Q (b,h,q,32)
    ushort* bufKh   = bufQh   + ROW_ELEMS;          // head-major K
    ushort* bufVt   = bufKh   + ROW_ELEMS;          // V chunked-transpose
    ushort* bufF_h  = bufVt   + ROW_ELEMS;          // 3276800 ffn hidden
    ushort* bufVal  = bufF_h  + (size_t)M_Q * D_FFN;   // 6 layers x 2785280
    ushort* src_h   = bufVal  + (size_t)NUM_LAYERS * M_V * D_MODEL;
    ushort* wpool   = src_h   + (size_t)M_V * D_MODEL;

    ushort* wq_h    = wpool;
    ushort* wk_h    = wq_h    + 393216;
    ushort* wv_h    = wk_h    + 393216;
    ushort* wo_h    = wv_h    + 393216;
    ushort* woff_h  = wo_h    + 393216;
    ushort* wattn_h = woff_h  + 393216;
    ushort* wval_h  = wattn_h + 196608;
    ushort* wout_h  = wval_h  + 393216;
    ushort* w1_h    = wout_h  + 393216;
    ushort* w2_h    = w1_h    + 1572864;

    float* out = (float*)d_out;

    // ---- conversions ----
    CvtArgs ca;
    ca.seg[0]  = { src,                    src_h,   (int)((size_t)M_V * D_MODEL / 4) };
    ca.seg[1]  = { (const float*)d_in[4],  wq_h,    393216 / 4 };
    ca.seg[2]  = { (const float*)d_in[6],  wk_h,    393216 / 4 };
    ca.seg[3]  = { (const float*)d_in[8],  wv_h,    393216 / 4 };
    ca.seg[4]  = { (const float*)d_in[10], wo_h,    393216 / 4 };
    ca.seg[5]  = { (const float*)d_in[14], woff_h,  393216 / 4 };
    ca.seg[6]  = { (const float*)d_in[16], wattn_h, 196608 / 4 };
    ca.seg[7]  = { (const float*)d_in[18], wval_h,  393216 / 4 };
    ca.seg[8]  = { (const float*)d_in[20], wout_h,  393216 / 4 };
    ca.seg[9]  = { (const float*)d_in[24], w1_h,    1572864 / 4 };
    ca.seg[10] = { (const float*)d_in[26], w2_h,    1572864 / 4 };
    convert_kernel<<<dim3(2720, 11), 256, 0, stream>>>(ca);

    init_out_kernel<<<800, 256, 0, stream>>>(tgt, qpos, out, out_h, qadd_h, (int)(ROW_ELEMS / 4));

    // Q pre-scale: log2(e)/sqrt(32) so attention computes exp2 directly
    const float QSCALE = 0.1767766952966369f * 1.4426950408889634f;
    const int MB_Q = M_Q / 64;   // 50
    const int MB_V = M_V / 64;   // 170

    // ---- ALL-LAYER value projections (depend only on src): one dispatch ----
    {
        GArgs gv;
        for (int l = 0; l < NUM_LAYERS; ++l) {
            const ushort* wl = wval_h + (size_t)l * 65536;
            const float* bv  = (const float*)d_in[19] + (size_t)l * 256;
            ushort* dst = bufVal + (size_t)l * M_V * D_MODEL;
            for (int i = 0; i < 4; ++i)
                gv.s[l * 4 + i] = { src_h, wl + (size_t)i * 64 * 256, bv + i * 64,
                                    dst + i * 64, 256, 2, MB_V, 1.f };
        }
        gemm_multi<<<dim3(MB_V, 24), 256, 0, stream>>>(gv, 256);
    }

    for (int l = 0; l < NUM_LAYERS; ++l) {
        const float* sa_b_q    = (const float*)d_in[5]  + (size_t)l * 256;
        const float* sa_b_k    = (const float*)d_in[7]  + (size_t)l * 256;
        const float* sa_b_v    = (const float*)d_in[9]  + (size_t)l * 256;
        const float* sa_b_o    = (const float*)d_in[11] + (size_t)l * 256;
        const float* ln2_g     = (const float*)d_in[12] + (size_t)l * 256;
        const float* ln2_b     = (const float*)d_in[13] + (size_t)l * 256;
        const float* ca_b_off  = (const float*)d_in[15] + (size_t)l * 256;
        const float* ca_b_attn = (const float*)d_in[17] + (size_t)l * 128;
        const float* ca_b_out  = (const float*)d_in[21] + (size_t)l * 256;
        const float* ln1_g     = (const float*)d_in[22] + (size_t)l * 256;
        const float* ln1_b     = (const float*)d_in[23] + (size_t)l * 256;
        const float* ffn_b1    = (const float*)d_in[25] + (size_t)l * 1024;
        const float* ffn_b2    = (const float*)d_in[27] + (size_t)l * 256;
        const float* ln3_g     = (const float*)d_in[28] + (size_t)l * 256;
        const float* ln3_b     = (const float*)d_in[29] + (size_t)l * 256;

        const ushort* wq = wq_h    + (size_t)l * 65536;
        const ushort* wk = wk_h    + (size_t)l * 65536;
        const ushort* wv = wv_h    + (size_t)l * 65536;
        const ushort* wo = wo_h    + (size_t)l * 65536;
        const ushort* wf = woff_h  + (size_t)l * 65536;
        const ushort* wa = wattn_h + (size_t)l * 32768;
        const ushort* wu = wout_h  + (size_t)l * 65536;
        const ushort* w1 = w1_h    + (size_t)l * 262144;
        const ushort* w2 = w2_h    + (size_t)l * 262144;

        ushort* valL = bufVal + (size_t)l * M_V * D_MODEL;

        GArgs ga;

        // ---- QKV projections (head-major / chunked-V), grid (50,12) ----
        for (int i = 0; i < 4; ++i) {
            ga.s[i]     = { qadd_h, wq + (size_t)i * 64 * 256, sa_b_q + i * 64,
                            bufQh + (size_t)(2 * i) * NQ * 32, 0, 4, MB_Q, QSCALE };
            ga.s[4 + i] = { qadd_h, wk + (size_t)i * 64 * 256, sa_b_k + i * 64,
                            bufKh + (size_t)(2 * i) * NQ * 32, 0, 4, MB_Q, 1.f };
            ga.s[8 + i] = { out_h,  wv + (size_t)i * 64 * 256, sa_b_v + i * 64,
                            bufVt + (size_t)(2 * i) * NQ * 32, 0, 5, MB_Q, 1.f };
        }
        gemm_multi<<<dim3(MB_Q, 12), 256, 0, stream>>>(ga, 256);

        attn_mfma<<<dim3(16, NQ / 32), 256, 0, stream>>>(bufQh, bufKh, bufVt, bufX_h);

        for (int i = 0; i < 4; ++i)
            ga.s[i] = { bufX_h, wo + (size_t)i * 64 * 256, sa_b_o + i * 64, bufT + i * 64, 256, 0, MB_Q, 1.f };
        gemm_multi<<<dim3(MB_Q, 4), 256, 0, stream>>>(ga, 256);

        residual_ln_kernel<<<M_Q, 256, 0, stream>>>(out, bufT, ln2_g, ln2_b, qpos, out, out_h, qadd_h);

        // ---- Deformable cross-attention ----
        for (int i = 0; i < 4; ++i)
            ga.s[i] = { qadd_h, wf + (size_t)i * 64 * 256, ca_b_off + i * 64, bufOff + i * 64, 256, 0, MB_Q, 1.f };
        for (int i = 0; i < 2; ++i)
            ga.s[4 + i] = { qadd_h, wa + (size_t)i * 64 * 256, ca_b_attn + i * 64, bufAw + i * 64, 128, 0, MB_Q, 1.f };
        gemm_multi<<<dim3(MB_Q, 6), 256, 0, stream>>>(ga, 256);

        sample_kernel<<<M_Q, 256, 0, stream>>>(valL, bufOff, bufAw, refp, bufX_h);

        for (int i = 0; i < 4; ++i)
            ga.s[i] = { bufX_h, wu + (size_t)i * 64 * 256, ca_b_out + i * 64, bufT + i * 64, 256, 0, MB_Q, 1.f };
        gemm_multi<<<dim3(MB_Q, 4), 256, 0, stream>>>(ga, 256);

        residual_ln_kernel<<<M_Q, 256, 0, stream>>>(out, bufT, ln1_g, ln1_b, qpos, out, out_h, qadd_h);

        // ---- FFN ----
        for (int i = 0; i < 16; ++i)
            ga.s[i] = { out_h, w1 + (size_t)i * 64 * 256, ffn_b1 + i * 64, bufF_h + i * 64, 1024, 1, MB_Q, 1.f };
        gemm_multi<<<dim3(MB_Q, 16), 256, 0, stream>>>(ga, 256);

        for (int i = 0; i < 4; ++i)
            ga.s[i] = { bufF_h, w2 + (size_t)i * 64 * 1024, ffn_b2 + i * 64, bufT + i * 64, 256, 0, MB_Q, 1.f };
        gemm_multi<<<dim3(MB_Q, 4), 256, 0, stream>>>(ga, 1024);

        residual_ln_kernel<<<M_Q, 256, 0, stream>>>(out, bufT, ln3_g, ln3_b, qpos, out, out_h, qadd_h);
    }

    (void)in_sizes; (void)n_in; (void)out_size; (void)ws_size;
}